// Round 19
// baseline (147.919 us; speedup 1.0000x reference)
//
#include <hip/hip_runtime.h>
#include <hip/hip_bf16.h>
#include <math.h>

#define B_ 4
#define N_ 256
#define D_ 128
#define H_ 256
#define K_ 8

typedef __attribute__((ext_vector_type(8))) short short8;
typedef __attribute__((ext_vector_type(4))) float f32x4;

__device__ __forceinline__ unsigned short f2bf(float x) {
    union { __hip_bfloat16 h; unsigned short s; } u;
    u.h = __float2bfloat16(x);
    return u.s;
}
__device__ __forceinline__ float bf2f(unsigned short b) {
    unsigned v = ((unsigned)b) << 16;
    return __builtin_bit_cast(float, v);
}
__device__ __forceinline__ unsigned pk2(float x, float y) {
    union { __hip_bfloat162 h; unsigned u; } c;
    c.h = __float22bfloat162_rn(float2{x, y});
    return c.u;
}
// async global->LDS, 16 B per lane (m97-verified width); no VGPR round-trip
__device__ __forceinline__ void gld_lds16(const float* g, float* l) {
    __builtin_amdgcn_global_load_lds(
        (const __attribute__((address_space(1))) void*)g,
        (__attribute__((address_space(3))) void*)l, 16, 0, 0);
}

// K0 v2 (unchanged from R18).
__global__ __launch_bounds__(256) void pre_kernel(
    const float* __restrict__ s, const float* __restrict__ W1,
    const float* __restrict__ b1,
    float* __restrict__ avec, float* __restrict__ bvec,
    unsigned short* __restrict__ Wt)
{
    int blk = blockIdx.x;
    int t = threadIdx.x;
    if (blk < 512) {
        int bi0 = blk * 2;
        __shared__ float s2[2][D_];
        {
            int r = t >> 7, d = t & 127;
            s2[r][d] = s[(size_t)(bi0 + r) * D_ + d];
        }
        __syncthreads();
        float aA0 = b1[t], aA1 = aA0, aB0 = 0.f, aB1 = 0.f;
        const float* W1a = W1 + t;
        const float* W1b = W1 + (size_t)D_ * H_ + t;
        #pragma unroll 8
        for (int d = 0; d < D_; ++d) {
            float wa = W1a[(size_t)d * H_];
            float wb = W1b[(size_t)d * H_];
            float s0 = s2[0][d], s1 = s2[1][d];
            aA0 = fmaf(s0, wa, aA0);
            aA1 = fmaf(s1, wa, aA1);
            aB0 = fmaf(s0, wb, aB0);
            aB1 = fmaf(s1, wb, aB1);
        }
        avec[(size_t)bi0 * H_ + t]       = aA0;
        avec[(size_t)(bi0 + 1) * H_ + t] = aA1;
        bvec[(size_t)bi0 * H_ + t]       = aB0;
        bvec[(size_t)(bi0 + 1) * H_ + t] = aB1;
    } else {
        int e = (blk - 512) * 256 + t;
        int h = e >> 7, d = e & 127;
        Wt[e] = f2bf(W1[(size_t)(2 * D_ + d) * H_ + h]);
    }
}

// K1 v4 (unchanged from R18 — R16's best).
__global__ __launch_bounds__(512, 2) void approx_scores(
    const float* __restrict__ s, const unsigned short* __restrict__ Wt,
    const float* __restrict__ W2, const float* __restrict__ b2,
    const float* __restrict__ avec, const float* __restrict__ bvec,
    unsigned short* __restrict__ ascu)
{
    int blk = blockIdx.x;              // 256 = b(4) x jt(4) x ic(16)
    int b   = blk >> 6;
    int jtb = ((blk >> 4) & 3) * 64;
    int i0  = (blk & 15) * 16;
    int t = threadIdx.x;
    int lane = t & 63;
    int w = __builtin_amdgcn_readfirstlane(t >> 6);
    int l15 = lane & 15, quad = lane >> 4;

    __shared__ __align__(16) short Pl[2][64 * 128];
    __shared__ __align__(16) float si_all[16][D_];
    __shared__ float partial[2][8][64];

    const float* sB = s + (size_t)b * N_ * D_;

    {
        int ii = t >> 5, dq = t & 31;
        *(float4*)&si_all[ii][dq * 4] =
            *(const float4*)(sB + (size_t)(i0 + ii) * D_ + dq * 4);
    }

    short8 Wreg[2][4];
    #pragma unroll
    for (int mi = 0; mi < 2; ++mi)
        #pragma unroll
        for (int dk = 0; dk < 4; ++dk)
            Wreg[mi][dk] = *(const short8*)(
                Wt + (size_t)(w * 32 + mi * 16 + l15) * D_ + dk * 32 + quad * 8);
    float bvr[2][4][4];
    float w2r[2][4];
    #pragma unroll
    for (int mi = 0; mi < 2; ++mi) {
        int hq = w * 32 + mi * 16 + quad * 4;
        #pragma unroll
        for (int r = 0; r < 4; ++r)
            w2r[mi][r] = W2[hq + r];
        #pragma unroll
        for (int nj = 0; nj < 4; ++nj)
            #pragma unroll
            for (int r = 0; r < 4; ++r)
                bvr[mi][nj][r] = bvec[((size_t)(b * N_ + jtb + nj * 16 + l15)) * H_
                                      + hq + r];
    }
    float b2v = b2[0];
    __syncthreads();

    {
        int row = t >> 3, seg = t & 7;
        const float* sj = sB + (size_t)(jtb + row) * D_ + seg * 16;
        float4 a0 = ((const float4*)sj)[0], a1 = ((const float4*)sj)[1];
        float4 a2 = ((const float4*)sj)[2], a3 = ((const float4*)sj)[3];
        const float* si = &si_all[0][seg * 16];
        float4 s0 = ((const float4*)si)[0], s1 = ((const float4*)si)[1];
        float4 s2 = ((const float4*)si)[2], s3 = ((const float4*)si)[3];
        uint4 v0, v1;
        v0.x = pk2(a0.x * s0.x, a0.y * s0.y); v0.y = pk2(a0.z * s0.z, a0.w * s0.w);
        v0.z = pk2(a1.x * s1.x, a1.y * s1.y); v0.w = pk2(a1.z * s1.z, a1.w * s1.w);
        v1.x = pk2(a2.x * s2.x, a2.y * s2.y); v1.y = pk2(a2.z * s2.z, a2.w * s2.w);
        v1.z = pk2(a3.x * s3.x, a3.y * s3.y); v1.w = pk2(a3.z * s3.z, a3.w * s3.w);
        int pc0 = (seg * 2) ^ (row & 15), pc1 = (seg * 2 + 1) ^ (row & 15);
        *(uint4*)&Pl[0][row * 128 + pc0 * 8] = v0;
        *(uint4*)&Pl[0][row * 128 + pc1 * 8] = v1;
    }
    __syncthreads();

    #pragma unroll 1
    for (int i = 0; i < 16; ++i) {
        int cur = i & 1;
        if (w == 0 && i > 0) {
            float sum = b2v;
            #pragma unroll
            for (int ww = 0; ww < 8; ++ww) sum += partial[(i - 1) & 1][ww][lane];
            ascu[(size_t)(b * N_ + i0 + i - 1) * N_ + jtb + lane] = f2bf(sum);
        }
        float avc[2][4];
        #pragma unroll
        for (int mi = 0; mi < 2; ++mi) {
            int hq = w * 32 + mi * 16 + quad * 4;
            #pragma unroll
            for (int r = 0; r < 4; ++r)
                avc[mi][r] = avec[(size_t)(b * N_ + i0 + i) * H_ + hq + r];
        }
        f32x4 acc[2][4];
        #pragma unroll
        for (int mi = 0; mi < 2; ++mi)
            #pragma unroll
            for (int nj = 0; nj < 4; ++nj)
                acc[mi][nj] = (f32x4){0.f, 0.f, 0.f, 0.f};
        #pragma unroll
        for (int dk = 0; dk < 4; ++dk) {
            short8 Pf[4];
            #pragma unroll
            for (int nj = 0; nj < 4; ++nj) {
                int pcc = (dk * 4 + quad) ^ l15;
                Pf[nj] = *(const short8*)&Pl[cur][(nj * 16 + l15) * 128 + pcc * 8];
            }
            #pragma unroll
            for (int nj = 0; nj < 4; ++nj)
                #pragma unroll
                for (int mi = 0; mi < 2; ++mi)
                    acc[mi][nj] = __builtin_amdgcn_mfma_f32_16x16x32_bf16(
                        Wreg[mi][dk], Pf[nj], acc[mi][nj], 0, 0, 0);
        }
        if (i < 15) {
            int row = t >> 3, seg = t & 7;
            const float* sj = sB + (size_t)(jtb + row) * D_ + seg * 16;
            float4 a0 = ((const float4*)sj)[0], a1 = ((const float4*)sj)[1];
            float4 a2 = ((const float4*)sj)[2], a3 = ((const float4*)sj)[3];
            const float* si = &si_all[i + 1][seg * 16];
            float4 s0 = ((const float4*)si)[0], s1 = ((const float4*)si)[1];
            float4 s2 = ((const float4*)si)[2], s3 = ((const float4*)si)[3];
            uint4 v0, v1;
            v0.x = pk2(a0.x * s0.x, a0.y * s0.y); v0.y = pk2(a0.z * s0.z, a0.w * s0.w);
            v0.z = pk2(a1.x * s1.x, a1.y * s1.y); v0.w = pk2(a1.z * s1.z, a1.w * s1.w);
            v1.x = pk2(a2.x * s2.x, a2.y * s2.y); v1.y = pk2(a2.z * s2.z, a2.w * s2.w);
            v1.z = pk2(a3.x * s3.x, a3.y * s3.y); v1.w = pk2(a3.z * s3.z, a3.w * s3.w);
            int pc0 = (seg * 2) ^ (row & 15), pc1 = (seg * 2 + 1) ^ (row & 15);
            *(uint4*)&Pl[cur ^ 1][row * 128 + pc0 * 8] = v0;
            *(uint4*)&Pl[cur ^ 1][row * 128 + pc1 * 8] = v1;
        }
        float rs[4];
        #pragma unroll
        for (int nj = 0; nj < 4; ++nj) rs[nj] = 0.f;
        #pragma unroll
        for (int mi = 0; mi < 2; ++mi)
            #pragma unroll
            for (int nj = 0; nj < 4; ++nj)
                #pragma unroll
                for (int r = 0; r < 4; ++r) {
                    float z = acc[mi][nj][r] + avc[mi][r] + bvr[mi][nj][r];
                    rs[nj] = fmaf(fmaxf(z, 0.f), w2r[mi][r], rs[nj]);
                }
        #pragma unroll
        for (int nj = 0; nj < 4; ++nj) {
            rs[nj] += __shfl_xor(rs[nj], 16);
            rs[nj] += __shfl_xor(rs[nj], 32);
        }
        float v = (quad == 0) ? rs[0] : (quad == 1) ? rs[1] : (quad == 2) ? rs[2] : rs[3];
        partial[cur][w][lane] = v;
        __syncthreads();
    }
    if (w == 0) {
        float sum = b2v;
        #pragma unroll
        for (int ww = 0; ww < 8; ++ww) sum += partial[15 & 1][ww][lane];
        ascu[(size_t)(b * N_ + i0 + 15) * N_ + jtb + lane] = f2bf(sum);
    }
}

// K2 v7: LDS-instruction-bound fix. R18 showed finalize = 110K LDS-pipe
// cyc/CU (4 seq-blocks x 2560 b128) = the measured 45 us. v7: 4 cands/thread
// (cg) -> 64 fma per 5 LDS insts (was 16), 4 rows/block x 256 blocks (1/CU,
// all resident, 1 pass). Wave owns 4 contiguous hg -> wv 2-way (free);
// Pt XOR-chunk swizzle + row stride 2064 -> pv <=2-way. W via v6's async
// DMA dbuf (no wpre regs). Per-CU LDS: ~31K cyc (~13 us).
#define DC2 16
#define PTRS 2064   // Pt row stride (floats): 128*16 + 16 -> r-banks offset 16
__global__ __launch_bounds__(256) void finalize_kernel(
    const float* __restrict__ s, const float* __restrict__ W1,
    const float* __restrict__ W2, const float* __restrict__ b2,
    const float* __restrict__ avec, const float* __restrict__ bvec,
    const unsigned short* __restrict__ ascu,
    float* __restrict__ ctx, float* __restrict__ gate, float* __restrict__ w)
{
    int bi0 = blockIdx.x * 4;          // 256 blocks, 4 rows each
    int b = bi0 >> 8;
    int t = threadIdx.x;               // 0..255

    __shared__ float asc[4][N_];                     // 4 KB
    __shared__ int cand[4][16];
    __shared__ __align__(16) float Pt[4 * PTRS];     // 33 KB [r][d][c] swizzled
    __shared__ __align__(16) float Wl[2][DC2 * H_];  // 32 KB DMA dbuf
    __shared__ float part[4][16][17];                // 4.4 KB
    __shared__ float rsc[4][16];
    __shared__ int sel8[4][8];

    // --- load approx scores: 4 per thread ---
    for (int e = t; e < 1024; e += 256) {
        int r = e >> 8, jj = e & 255;
        asc[r][jj] = bf2f(ascu[(size_t)(bi0 + r) * N_ + jj]);
    }
    __syncthreads();

    // --- rank-select top-16: wave = row, thread ranks 4 j's, single asc sweep ---
    {
        int r = t >> 6, lj = t & 63;
        float my[4]; int rk[4];
        #pragma unroll
        for (int m = 0; m < 4; ++m) { my[m] = asc[r][m * 64 + lj]; rk[m] = 0; }
        #pragma unroll 4
        for (int j2 = 0; j2 < N_; ++j2) {
            float o = asc[r][j2];
            #pragma unroll
            for (int m = 0; m < 4; ++m) {
                int jm = m * 64 + lj;
                rk[m] += (o > my[m]) || (o == my[m] && j2 < jm);
            }
        }
        #pragma unroll
        for (int m = 0; m < 4; ++m)
            if (rk[m] < 16) cand[r][rk[m]] = m * 64 + lj;
    }
    __syncthreads();

    const float* Wc = W1 + (size_t)2 * D_ * H_;      // W1c[d][h]

    // issue async DMA of W chunk 0 (16 KB, 4 slots/thread, lane-contiguous)
    #pragma unroll
    for (int k = 0; k < 4; ++k) {
        int slot = t + 256 * k;
        gld_lds16(Wc + slot * 4, &Wl[0][slot * 4]);
    }

    // --- build Pt[r][d][c], chunk-swizzled: phys4chunk = (c>>2) ^ r ---
    for (int e = t; e < 2048; e += 256) {
        int rr = e >> 9, c = (e >> 5) & 15, dq = e & 31;
        int j = cand[rr][c];
        float4 sj = *(const float4*)(s + ((size_t)(b * N_ + j)) * D_ + dq * 4);
        float4 si = *(const float4*)(s + ((size_t)(bi0 + rr)) * D_ + dq * 4);
        int pc = ((c >> 2) ^ rr) & 3;
        int base = rr * PTRS + (dq * 4) * 16 + pc * 4 + (c & 3);
        Pt[base + 0 * 16] = si.x * sj.x;
        Pt[base + 1 * 16] = si.y * sj.y;
        Pt[base + 2 * 16] = si.z * sj.z;
        Pt[base + 3 * 16] = si.w * sj.w;
    }

    // --- acc init: exact fp32 a_i[h] + b_j[h] for 4 cands x 16 h ---
    int cg = t & 3, rr = (t >> 2) & 3;
    int hg = (t >> 6) * 4 + ((t >> 4) & 3);   // wave owns 4 contiguous hg
    int h0 = hg * 16;
    float acc[4][16];
    {
        const float* av = avec + (size_t)(bi0 + rr) * H_ + h0;
        float4 av4[4];
        #pragma unroll
        for (int m4 = 0; m4 < 4; ++m4) av4[m4] = *(const float4*)(av + m4 * 4);
        #pragma unroll
        for (int cc = 0; cc < 4; ++cc) {
            int j = cand[rr][cg * 4 + cc];
            const float* bv = bvec + ((size_t)(b * N_ + j)) * H_ + h0;
            #pragma unroll
            for (int m4 = 0; m4 < 4; ++m4) {
                float4 b4 = *(const float4*)(bv + m4 * 4);
                acc[cc][m4 * 4 + 0] = av4[m4].x + b4.x;
                acc[cc][m4 * 4 + 1] = av4[m4].y + b4.y;
                acc[cc][m4 * 4 + 2] = av4[m4].z + b4.z;
                acc[cc][m4 * 4 + 3] = av4[m4].w + b4.w;
            }
        }
    }
    __syncthreads();   // drains chunk-0 DMA + Pt writes

    // --- K-chunked GEMM, async double-buffered W ---
    int pvoff = rr * PTRS + ((cg ^ rr) & 3) * 4;
    #pragma unroll 1
    for (int ch = 0; ch < 8; ++ch) {
        int cur = ch & 1;
        if (ch < 7) {
            const float* src = Wc + (size_t)(ch + 1) * DC2 * H_;
            #pragma unroll
            for (int k = 0; k < 4; ++k) {
                int slot = t + 256 * k;
                gld_lds16(src + slot * 4, &Wl[cur ^ 1][slot * 4]);
            }
        }
        int d0 = ch * DC2;
        #pragma unroll
        for (int d = 0; d < DC2; ++d) {
            float4 pv = *(const float4*)&Pt[pvoff + (d0 + d) * 16];
            float wv[16];
            *(float4*)&wv[0]  = *(const float4*)&Wl[cur][d * H_ + h0];
            *(float4*)&wv[4]  = *(const float4*)&Wl[cur][d * H_ + h0 + 4];
            *(float4*)&wv[8]  = *(const float4*)&Wl[cur][d * H_ + h0 + 8];
            *(float4*)&wv[12] = *(const float4*)&Wl[cur][d * H_ + h0 + 12];
            #pragma unroll
            for (int m = 0; m < 16; ++m) {
                acc[0][m] = fmaf(pv.x, wv[m], acc[0][m]);
                acc[1][m] = fmaf(pv.y, wv[m], acc[1][m]);
                acc[2][m] = fmaf(pv.z, wv[m], acc[2][m]);
                acc[3][m] = fmaf(pv.w, wv[m], acc[3][m]);
            }
        }
        __syncthreads();
    }

    // --- epilogue: relu * W2 partial per (r, cand), reduce over 16 hg ---
    {
        float w2v[16];
        *(float4*)&w2v[0]  = *(const float4*)(W2 + h0);
        *(float4*)&w2v[4]  = *(const float4*)(W2 + h0 + 4);
        *(float4*)&w2v[8]  = *(const float4*)(W2 + h0 + 8);
        *(float4*)&w2v[12] = *(const float4*)(W2 + h0 + 12);
        #pragma unroll
        for (int cc = 0; cc < 4; ++cc) {
            float sc = 0.f;
            #pragma unroll
            for (int m = 0; m < 16; ++m)
                sc = fmaf(fmaxf(acc[cc][m], 0.f), w2v[m], sc);
            part[rr][cg * 4 + cc][hg] = sc;
        }
    }
    __syncthreads();
    if (t < 64) {
        int r2 = t >> 4, c2 = t & 15;
        float sum = b2[0];
        #pragma unroll
        for (int m = 0; m < 16; ++m) sum += part[r2][c2][m];
        rsc[r2][c2] = sum;
    }
    __syncthreads();

    // top-8 among 16 exact scores, tiebreak smaller original index
    if (t < 64) {
        int r2 = t >> 4, c2 = t & 15;
        float my = rsc[r2][c2]; int myj = cand[r2][c2];
        int rank = 0;
        #pragma unroll
        for (int c3 = 0; c3 < 16; ++c3) {
            float o = rsc[r2][c3]; int oj = cand[r2][c3];
            rank += (o > my) || (o == my && oj < myj);
        }
        if (rank < 8) sel8[r2][rank] = myj;
    }
    __syncthreads();

    // gate / w: 4 rows x 256 j
    for (int e = t; e < 1024; e += 256) {
        int r2 = e >> 8, jj = e & 255;
        float gv = 0.f;
        #pragma unroll
        for (int m = 0; m < 8; ++m)
            gv = (jj == sel8[r2][m]) ? 1.f : gv;
        gate[(size_t)(bi0 + r2) * N_ + jj] = gv;
        w[(size_t)(bi0 + r2) * N_ + jj]    = gv * 0.125f;
    }
    // ctx: 4 rows x 128 d
    for (int e = t; e < 512; e += 256) {
        int r2 = e >> 7, d = e & 127;
        float a = 0.f;
        #pragma unroll
        for (int m = 0; m < 8; ++m)
            a += s[((size_t)(b * N_ + sel8[r2][m])) * D_ + d];
        ctx[(size_t)(bi0 + r2) * D_ + d] = a * 0.125f;
    }
}

extern "C" void kernel_launch(void* const* d_in, const int* in_sizes, int n_in,
                              void* d_out, int out_size, void* d_ws, size_t ws_size,
                              hipStream_t stream)
{
    const float* s  = (const float*)d_in[0];
    const float* W1 = (const float*)d_in[1];
    const float* b1 = (const float*)d_in[2];
    const float* W2 = (const float*)d_in[3];
    const float* b2 = (const float*)d_in[4];

    float* avec = (float*)d_ws;                                           // 262144 f
    float* bvec = avec + (size_t)B_ * N_ * H_;                            // 262144 f
    unsigned short* ascu = (unsigned short*)(bvec + (size_t)B_ * N_ * H_);// 262144 us
    unsigned short* Wtu  = ascu + (size_t)B_ * N_ * N_;                   // 32768 us

    float* ctx  = (float*)d_out;
    float* gate = ctx + (size_t)B_ * N_ * D_;
    float* wout = gate + (size_t)B_ * N_ * N_;

    pre_kernel<<<640, 256, 0, stream>>>(s, W1, b1, avec, bvec, Wtu);
    approx_scores<<<256, 512, 0, stream>>>(s, Wtu, W2, b2, avec, bvec, ascu);
    finalize_kernel<<<B_ * N_ / 4, 256, 0, stream>>>(s, W1, W2, b2, avec, bvec, ascu,
                                                     ctx, gate, wout);
}

// Round 20
// 142.918 us; speedup vs baseline: 1.0350x; 1.0350x over previous
//
#include <hip/hip_runtime.h>
#include <hip/hip_bf16.h>
#include <math.h>

#define B_ 4
#define N_ 256
#define D_ 128
#define H_ 256
#define K_ 8

typedef __attribute__((ext_vector_type(8))) short short8;
typedef __attribute__((ext_vector_type(4))) float f32x4;

__device__ __forceinline__ unsigned short f2bf(float x) {
    union { __hip_bfloat16 h; unsigned short s; } u;
    u.h = __float2bfloat16(x);
    return u.s;
}
__device__ __forceinline__ float bf2f(unsigned short b) {
    unsigned v = ((unsigned)b) << 16;
    return __builtin_bit_cast(float, v);
}
__device__ __forceinline__ unsigned pk2(float x, float y) {
    union { __hip_bfloat162 h; unsigned u; } c;
    c.h = __float22bfloat162_rn(float2{x, y});
    return c.u;
}
// async global->LDS, 16 B per lane (m97-verified width); no VGPR round-trip
__device__ __forceinline__ void gld_lds16(const float* g, float* l) {
    __builtin_amdgcn_global_load_lds(
        (const __attribute__((address_space(1))) void*)g,
        (__attribute__((address_space(3))) void*)l, 16, 0, 0);
}

// K0 v2 (unchanged).
__global__ __launch_bounds__(256) void pre_kernel(
    const float* __restrict__ s, const float* __restrict__ W1,
    const float* __restrict__ b1,
    float* __restrict__ avec, float* __restrict__ bvec,
    unsigned short* __restrict__ Wt)
{
    int blk = blockIdx.x;
    int t = threadIdx.x;
    if (blk < 512) {
        int bi0 = blk * 2;
        __shared__ float s2[2][D_];
        {
            int r = t >> 7, d = t & 127;
            s2[r][d] = s[(size_t)(bi0 + r) * D_ + d];
        }
        __syncthreads();
        float aA0 = b1[t], aA1 = aA0, aB0 = 0.f, aB1 = 0.f;
        const float* W1a = W1 + t;
        const float* W1b = W1 + (size_t)D_ * H_ + t;
        #pragma unroll 8
        for (int d = 0; d < D_; ++d) {
            float wa = W1a[(size_t)d * H_];
            float wb = W1b[(size_t)d * H_];
            float s0 = s2[0][d], s1 = s2[1][d];
            aA0 = fmaf(s0, wa, aA0);
            aA1 = fmaf(s1, wa, aA1);
            aB0 = fmaf(s0, wb, aB0);
            aB1 = fmaf(s1, wb, aB1);
        }
        avec[(size_t)bi0 * H_ + t]       = aA0;
        avec[(size_t)(bi0 + 1) * H_ + t] = aA1;
        bvec[(size_t)bi0 * H_ + t]       = aB0;
        bvec[(size_t)(bi0 + 1) * H_ + t] = aB1;
    } else {
        int e = (blk - 512) * 256 + t;
        int h = e >> 7, d = e & 127;
        Wt[e] = f2bf(W1[(size_t)(2 * D_ + d) * H_ + h]);
    }
}

// K1 v4 (unchanged — R16's best).
__global__ __launch_bounds__(512, 2) void approx_scores(
    const float* __restrict__ s, const unsigned short* __restrict__ Wt,
    const float* __restrict__ W2, const float* __restrict__ b2,
    const float* __restrict__ avec, const float* __restrict__ bvec,
    unsigned short* __restrict__ ascu)
{
    int blk = blockIdx.x;              // 256 = b(4) x jt(4) x ic(16)
    int b   = blk >> 6;
    int jtb = ((blk >> 4) & 3) * 64;
    int i0  = (blk & 15) * 16;
    int t = threadIdx.x;
    int lane = t & 63;
    int w = __builtin_amdgcn_readfirstlane(t >> 6);
    int l15 = lane & 15, quad = lane >> 4;

    __shared__ __align__(16) short Pl[2][64 * 128];
    __shared__ __align__(16) float si_all[16][D_];
    __shared__ float partial[2][8][64];

    const float* sB = s + (size_t)b * N_ * D_;

    {
        int ii = t >> 5, dq = t & 31;
        *(float4*)&si_all[ii][dq * 4] =
            *(const float4*)(sB + (size_t)(i0 + ii) * D_ + dq * 4);
    }

    short8 Wreg[2][4];
    #pragma unroll
    for (int mi = 0; mi < 2; ++mi)
        #pragma unroll
        for (int dk = 0; dk < 4; ++dk)
            Wreg[mi][dk] = *(const short8*)(
                Wt + (size_t)(w * 32 + mi * 16 + l15) * D_ + dk * 32 + quad * 8);
    float bvr[2][4][4];
    float w2r[2][4];
    #pragma unroll
    for (int mi = 0; mi < 2; ++mi) {
        int hq = w * 32 + mi * 16 + quad * 4;
        #pragma unroll
        for (int r = 0; r < 4; ++r)
            w2r[mi][r] = W2[hq + r];
        #pragma unroll
        for (int nj = 0; nj < 4; ++nj)
            #pragma unroll
            for (int r = 0; r < 4; ++r)
                bvr[mi][nj][r] = bvec[((size_t)(b * N_ + jtb + nj * 16 + l15)) * H_
                                      + hq + r];
    }
    float b2v = b2[0];
    __syncthreads();

    {
        int row = t >> 3, seg = t & 7;
        const float* sj = sB + (size_t)(jtb + row) * D_ + seg * 16;
        float4 a0 = ((const float4*)sj)[0], a1 = ((const float4*)sj)[1];
        float4 a2 = ((const float4*)sj)[2], a3 = ((const float4*)sj)[3];
        const float* si = &si_all[0][seg * 16];
        float4 s0 = ((const float4*)si)[0], s1 = ((const float4*)si)[1];
        float4 s2 = ((const float4*)si)[2], s3 = ((const float4*)si)[3];
        uint4 v0, v1;
        v0.x = pk2(a0.x * s0.x, a0.y * s0.y); v0.y = pk2(a0.z * s0.z, a0.w * s0.w);
        v0.z = pk2(a1.x * s1.x, a1.y * s1.y); v0.w = pk2(a1.z * s1.z, a1.w * s1.w);
        v1.x = pk2(a2.x * s2.x, a2.y * s2.y); v1.y = pk2(a2.z * s2.z, a2.w * s2.w);
        v1.z = pk2(a3.x * s3.x, a3.y * s3.y); v1.w = pk2(a3.z * s3.z, a3.w * s3.w);
        int pc0 = (seg * 2) ^ (row & 15), pc1 = (seg * 2 + 1) ^ (row & 15);
        *(uint4*)&Pl[0][row * 128 + pc0 * 8] = v0;
        *(uint4*)&Pl[0][row * 128 + pc1 * 8] = v1;
    }
    __syncthreads();

    #pragma unroll 1
    for (int i = 0; i < 16; ++i) {
        int cur = i & 1;
        if (w == 0 && i > 0) {
            float sum = b2v;
            #pragma unroll
            for (int ww = 0; ww < 8; ++ww) sum += partial[(i - 1) & 1][ww][lane];
            ascu[(size_t)(b * N_ + i0 + i - 1) * N_ + jtb + lane] = f2bf(sum);
        }
        float avc[2][4];
        #pragma unroll
        for (int mi = 0; mi < 2; ++mi) {
            int hq = w * 32 + mi * 16 + quad * 4;
            #pragma unroll
            for (int r = 0; r < 4; ++r)
                avc[mi][r] = avec[(size_t)(b * N_ + i0 + i) * H_ + hq + r];
        }
        f32x4 acc[2][4];
        #pragma unroll
        for (int mi = 0; mi < 2; ++mi)
            #pragma unroll
            for (int nj = 0; nj < 4; ++nj)
                acc[mi][nj] = (f32x4){0.f, 0.f, 0.f, 0.f};
        #pragma unroll
        for (int dk = 0; dk < 4; ++dk) {
            short8 Pf[4];
            #pragma unroll
            for (int nj = 0; nj < 4; ++nj) {
                int pcc = (dk * 4 + quad) ^ l15;
                Pf[nj] = *(const short8*)&Pl[cur][(nj * 16 + l15) * 128 + pcc * 8];
            }
            #pragma unroll
            for (int nj = 0; nj < 4; ++nj)
                #pragma unroll
                for (int mi = 0; mi < 2; ++mi)
                    acc[mi][nj] = __builtin_amdgcn_mfma_f32_16x16x32_bf16(
                        Wreg[mi][dk], Pf[nj], acc[mi][nj], 0, 0, 0);
        }
        if (i < 15) {
            int row = t >> 3, seg = t & 7;
            const float* sj = sB + (size_t)(jtb + row) * D_ + seg * 16;
            float4 a0 = ((const float4*)sj)[0], a1 = ((const float4*)sj)[1];
            float4 a2 = ((const float4*)sj)[2], a3 = ((const float4*)sj)[3];
            const float* si = &si_all[i + 1][seg * 16];
            float4 s0 = ((const float4*)si)[0], s1 = ((const float4*)si)[1];
            float4 s2 = ((const float4*)si)[2], s3 = ((const float4*)si)[3];
            uint4 v0, v1;
            v0.x = pk2(a0.x * s0.x, a0.y * s0.y); v0.y = pk2(a0.z * s0.z, a0.w * s0.w);
            v0.z = pk2(a1.x * s1.x, a1.y * s1.y); v0.w = pk2(a1.z * s1.z, a1.w * s1.w);
            v1.x = pk2(a2.x * s2.x, a2.y * s2.y); v1.y = pk2(a2.z * s2.z, a2.w * s2.w);
            v1.z = pk2(a3.x * s3.x, a3.y * s3.y); v1.w = pk2(a3.z * s3.z, a3.w * s3.w);
            int pc0 = (seg * 2) ^ (row & 15), pc1 = (seg * 2 + 1) ^ (row & 15);
            *(uint4*)&Pl[cur ^ 1][row * 128 + pc0 * 8] = v0;
            *(uint4*)&Pl[cur ^ 1][row * 128 + pc1 * 8] = v1;
        }
        float rs[4];
        #pragma unroll
        for (int nj = 0; nj < 4; ++nj) rs[nj] = 0.f;
        #pragma unroll
        for (int mi = 0; mi < 2; ++mi)
            #pragma unroll
            for (int nj = 0; nj < 4; ++nj)
                #pragma unroll
                for (int r = 0; r < 4; ++r) {
                    float z = acc[mi][nj][r] + avc[mi][r] + bvr[mi][nj][r];
                    rs[nj] = fmaf(fmaxf(z, 0.f), w2r[mi][r], rs[nj]);
                }
        #pragma unroll
        for (int nj = 0; nj < 4; ++nj) {
            rs[nj] += __shfl_xor(rs[nj], 16);
            rs[nj] += __shfl_xor(rs[nj], 32);
        }
        float v = (quad == 0) ? rs[0] : (quad == 1) ? rs[1] : (quad == 2) ? rs[2] : rs[3];
        partial[cur][w][lane] = v;
        __syncthreads();
    }
    if (w == 0) {
        float sum = b2v;
        #pragma unroll
        for (int ww = 0; ww < 8; ++ww) sum += partial[15 & 1][ww][lane];
        ascu[(size_t)(b * N_ + i0 + 15) * N_ + jtb + lane] = f2bf(sum);
    }
}

// K2 v8: v7's 4-cands/thread shape (proven spill-free, VGPR 124) with the two
// measured bugs fixed: (1) Pt d-major, addr = d*64 + rr*16 + c -> the 16
// per-wave pv-float4 addrs tile banks exactly 2x (free); v7's PTRS=2064 made
// rows 0/2 and 1/3 collide (2.04M conflict-cyc). (2) Wl dbuf at DC2=8
// (2x8 KB): LDS 75->58 KB -> 2 blocks/CU (v7 was 1 block/CU, 10% occupancy).
#define DC8 8
__global__ __launch_bounds__(256) void finalize_kernel(
    const float* __restrict__ s, const float* __restrict__ W1,
    const float* __restrict__ W2, const float* __restrict__ b2,
    const float* __restrict__ avec, const float* __restrict__ bvec,
    const unsigned short* __restrict__ ascu,
    float* __restrict__ ctx, float* __restrict__ gate, float* __restrict__ w)
{
    int bi0 = blockIdx.x * 4;          // 256 blocks, 4 rows each
    int b = bi0 >> 8;
    int t = threadIdx.x;               // 0..255

    __shared__ float asc[4][N_];                     // 4 KB
    __shared__ int cand[4][16];
    __shared__ __align__(16) float Pt[D_ * 64];      // 32 KB, addr d*64+rr*16+c
    __shared__ __align__(16) float Wl[2][DC8 * H_];  // 16 KB DMA dbuf
    __shared__ float part[4][16][17];                // 4.4 KB
    __shared__ float rsc[4][16];
    __shared__ int sel8[4][8];

    // --- load approx scores: 4 per thread ---
    for (int e = t; e < 1024; e += 256) {
        int r = e >> 8, jj = e & 255;
        asc[r][jj] = bf2f(ascu[(size_t)(bi0 + r) * N_ + jj]);
    }
    __syncthreads();

    // --- rank-select top-16: wave = row, thread ranks 4 j's ---
    {
        int r = t >> 6, lj = t & 63;
        float my[4]; int rk[4];
        #pragma unroll
        for (int m = 0; m < 4; ++m) { my[m] = asc[r][m * 64 + lj]; rk[m] = 0; }
        #pragma unroll 4
        for (int j2 = 0; j2 < N_; ++j2) {
            float o = asc[r][j2];
            #pragma unroll
            for (int m = 0; m < 4; ++m) {
                int jm = m * 64 + lj;
                rk[m] += (o > my[m]) || (o == my[m] && j2 < jm);
            }
        }
        #pragma unroll
        for (int m = 0; m < 4; ++m)
            if (rk[m] < 16) cand[r][rk[m]] = m * 64 + lj;
    }
    __syncthreads();

    const float* Wc = W1 + (size_t)2 * D_ * H_;      // W1c[d][h]

    // issue async DMA of W chunk 0 (8 KB = 512 x 16 B; 2 slots/thread)
    #pragma unroll
    for (int k = 0; k < 2; ++k) {
        int slot = t + 256 * k;
        gld_lds16(Wc + slot * 4, &Wl[0][slot * 4]);
    }

    // --- build Pt: Pt[d*64 + rr*16 + c] = s_i[d]*s_j[d] ---
    for (int e = t; e < 2048; e += 256) {
        int rr = e >> 9, c = e & 15, dq = (e >> 4) & 31;
        int j = cand[rr][c];
        float4 sj = *(const float4*)(s + ((size_t)(b * N_ + j)) * D_ + dq * 4);
        float4 si = *(const float4*)(s + ((size_t)(bi0 + rr)) * D_ + dq * 4);
        int base = (dq * 4) * 64 + rr * 16 + c;
        Pt[base + 0 * 64] = si.x * sj.x;
        Pt[base + 1 * 64] = si.y * sj.y;
        Pt[base + 2 * 64] = si.z * sj.z;
        Pt[base + 3 * 64] = si.w * sj.w;
    }

    // --- acc init: exact fp32 a_i[h] + b_j[h] for 4 cands x 16 h ---
    int cg = t & 3, rr = (t >> 2) & 3;
    int hg = (t >> 6) * 4 + ((t >> 4) & 3);   // wave owns 4 contiguous hg
    int h0 = hg * 16;
    float acc[4][16];
    {
        const float* av = avec + (size_t)(bi0 + rr) * H_ + h0;
        float4 av4[4];
        #pragma unroll
        for (int m4 = 0; m4 < 4; ++m4) av4[m4] = *(const float4*)(av + m4 * 4);
        #pragma unroll
        for (int cc = 0; cc < 4; ++cc) {
            int j = cand[rr][cg * 4 + cc];
            const float* bv = bvec + ((size_t)(b * N_ + j)) * H_ + h0;
            #pragma unroll
            for (int m4 = 0; m4 < 4; ++m4) {
                float4 b4 = *(const float4*)(bv + m4 * 4);
                acc[cc][m4 * 4 + 0] = av4[m4].x + b4.x;
                acc[cc][m4 * 4 + 1] = av4[m4].y + b4.y;
                acc[cc][m4 * 4 + 2] = av4[m4].z + b4.z;
                acc[cc][m4 * 4 + 3] = av4[m4].w + b4.w;
            }
        }
    }
    __syncthreads();   // drains chunk-0 DMA + Pt writes

    // --- K-chunked GEMM (16 chunks of 8 d), async double-buffered W ---
    int pvoff = rr * 16 + cg * 4;
    #pragma unroll 1
    for (int ch = 0; ch < 16; ++ch) {
        int cur = ch & 1;
        if (ch < 15) {
            const float* src = Wc + (size_t)(ch + 1) * DC8 * H_;
            #pragma unroll
            for (int k = 0; k < 2; ++k) {
                int slot = t + 256 * k;
                gld_lds16(src + slot * 4, &Wl[cur ^ 1][slot * 4]);
            }
        }
        int d0 = ch * DC8;
        #pragma unroll
        for (int d = 0; d < DC8; ++d) {
            float4 pv = *(const float4*)&Pt[(d0 + d) * 64 + pvoff];
            float wv[16];
            *(float4*)&wv[0]  = *(const float4*)&Wl[cur][d * H_ + h0];
            *(float4*)&wv[4]  = *(const float4*)&Wl[cur][d * H_ + h0 + 4];
            *(float4*)&wv[8]  = *(const float4*)&Wl[cur][d * H_ + h0 + 8];
            *(float4*)&wv[12] = *(const float4*)&Wl[cur][d * H_ + h0 + 12];
            #pragma unroll
            for (int m = 0; m < 16; ++m) {
                acc[0][m] = fmaf(pv.x, wv[m], acc[0][m]);
                acc[1][m] = fmaf(pv.y, wv[m], acc[1][m]);
                acc[2][m] = fmaf(pv.z, wv[m], acc[2][m]);
                acc[3][m] = fmaf(pv.w, wv[m], acc[3][m]);
            }
        }
        __syncthreads();
    }

    // --- epilogue: relu * W2 partial per (r, cand), reduce over 16 hg ---
    {
        float w2v[16];
        *(float4*)&w2v[0]  = *(const float4*)(W2 + h0);
        *(float4*)&w2v[4]  = *(const float4*)(W2 + h0 + 4);
        *(float4*)&w2v[8]  = *(const float4*)(W2 + h0 + 8);
        *(float4*)&w2v[12] = *(const float4*)(W2 + h0 + 12);
        #pragma unroll
        for (int cc = 0; cc < 4; ++cc) {
            float sc = 0.f;
            #pragma unroll
            for (int m = 0; m < 16; ++m)
                sc = fmaf(fmaxf(acc[cc][m], 0.f), w2v[m], sc);
            part[rr][cg * 4 + cc][hg] = sc;
        }
    }
    __syncthreads();
    if (t < 64) {
        int r2 = t >> 4, c2 = t & 15;
        float sum = b2[0];
        #pragma unroll
        for (int m = 0; m < 16; ++m) sum += part[r2][c2][m];
        rsc[r2][c2] = sum;
    }
    __syncthreads();

    // top-8 among 16 exact scores, tiebreak smaller original index
    if (t < 64) {
        int r2 = t >> 4, c2 = t & 15;
        float my = rsc[r2][c2]; int myj = cand[r2][c2];
        int rank = 0;
        #pragma unroll
        for (int c3 = 0; c3 < 16; ++c3) {
            float o = rsc[r2][c3]; int oj = cand[r2][c3];
            rank += (o > my) || (o == my && oj < myj);
        }
        if (rank < 8) sel8[r2][rank] = myj;
    }
    __syncthreads();

    // gate / w: 4 rows x 256 j
    for (int e = t; e < 1024; e += 256) {
        int r2 = e >> 8, jj = e & 255;
        float gv = 0.f;
        #pragma unroll
        for (int m = 0; m < 8; ++m)
            gv = (jj == sel8[r2][m]) ? 1.f : gv;
        gate[(size_t)(bi0 + r2) * N_ + jj] = gv;
        w[(size_t)(bi0 + r2) * N_ + jj]    = gv * 0.125f;
    }
    // ctx: 4 rows x 128 d
    for (int e = t; e < 512; e += 256) {
        int r2 = e >> 7, d = e & 127;
        float a = 0.f;
        #pragma unroll
        for (int m = 0; m < 8; ++m)
            a += s[((size_t)(b * N_ + sel8[r2][m])) * D_ + d];
        ctx[(size_t)(bi0 + r2) * D_ + d] = a * 0.125f;
    }
}

extern "C" void kernel_launch(void* const* d_in, const int* in_sizes, int n_in,
                              void* d_out, int out_size, void* d_ws, size_t ws_size,
                              hipStream_t stream)
{
    const float* s  = (const float*)d_in[0];
    const float* W1 = (const float*)d_in[1];
    const float* b1 = (const float*)d_in[2];
    const float* W2 = (const float*)d_in[3];
    const float* b2 = (const float*)d_in[4];

    float* avec = (float*)d_ws;                                           // 262144 f
    float* bvec = avec + (size_t)B_ * N_ * H_;                            // 262144 f
    unsigned short* ascu = (unsigned short*)(bvec + (size_t)B_ * N_ * H_);// 262144 us
    unsigned short* Wtu  = ascu + (size_t)B_ * N_ * N_;                   // 32768 us

    float* ctx  = (float*)d_out;
    float* gate = ctx + (size_t)B_ * N_ * D_;
    float* wout = gate + (size_t)B_ * N_ * N_;

    pre_kernel<<<640, 256, 0, stream>>>(s, W1, b1, avec, bvec, Wtu);
    approx_scores<<<256, 512, 0, stream>>>(s, Wtu, W2, b2, avec, bvec, ascu);
    finalize_kernel<<<B_ * N_ / 4, 256, 0, stream>>>(s, W1, W2, b2, avec, bvec, ascu,
                                                     ctx, gate, wout);
}

// Round 21
// 136.588 us; speedup vs baseline: 1.0830x; 1.0463x over previous
//
#include <hip/hip_runtime.h>
#include <hip/hip_bf16.h>
#include <math.h>

#define B_ 4
#define N_ 256
#define D_ 128
#define H_ 256
#define K_ 8

typedef __attribute__((ext_vector_type(8))) short short8;
typedef __attribute__((ext_vector_type(4))) float f32x4;

__device__ __forceinline__ unsigned short f2bf(float x) {
    union { __hip_bfloat16 h; unsigned short s; } u;
    u.h = __float2bfloat16(x);
    return u.s;
}
__device__ __forceinline__ float bf2f(unsigned short b) {
    unsigned v = ((unsigned)b) << 16;
    return __builtin_bit_cast(float, v);
}
__device__ __forceinline__ unsigned pk2(float x, float y) {
    union { __hip_bfloat162 h; unsigned u; } c;
    c.h = __float22bfloat162_rn(float2{x, y});
    return c.u;
}
// async global->LDS, 16 B per lane (m97-verified width); no VGPR round-trip
__device__ __forceinline__ void gld_lds16(const float* g, float* l) {
    __builtin_amdgcn_global_load_lds(
        (const __attribute__((address_space(1))) void*)g,
        (__attribute__((address_space(3))) void*)l, 16, 0, 0);
}

// K0 v2 (unchanged).
__global__ __launch_bounds__(256) void pre_kernel(
    const float* __restrict__ s, const float* __restrict__ W1,
    const float* __restrict__ b1,
    float* __restrict__ avec, float* __restrict__ bvec,
    unsigned short* __restrict__ Wt)
{
    int blk = blockIdx.x;
    int t = threadIdx.x;
    if (blk < 512) {
        int bi0 = blk * 2;
        __shared__ float s2[2][D_];
        {
            int r = t >> 7, d = t & 127;
            s2[r][d] = s[(size_t)(bi0 + r) * D_ + d];
        }
        __syncthreads();
        float aA0 = b1[t], aA1 = aA0, aB0 = 0.f, aB1 = 0.f;
        const float* W1a = W1 + t;
        const float* W1b = W1 + (size_t)D_ * H_ + t;
        #pragma unroll 8
        for (int d = 0; d < D_; ++d) {
            float wa = W1a[(size_t)d * H_];
            float wb = W1b[(size_t)d * H_];
            float s0 = s2[0][d], s1 = s2[1][d];
            aA0 = fmaf(s0, wa, aA0);
            aA1 = fmaf(s1, wa, aA1);
            aB0 = fmaf(s0, wb, aB0);
            aB1 = fmaf(s1, wb, aB1);
        }
        avec[(size_t)bi0 * H_ + t]       = aA0;
        avec[(size_t)(bi0 + 1) * H_ + t] = aA1;
        bvec[(size_t)bi0 * H_ + t]       = aB0;
        bvec[(size_t)(bi0 + 1) * H_ + t] = aB1;
    } else {
        int e = (blk - 512) * 256 + t;
        int h = e >> 7, d = e & 127;
        Wt[e] = f2bf(W1[(size_t)(2 * D_ + d) * H_ + h]);
    }
}

// K1 v4 (unchanged — R16's best).
__global__ __launch_bounds__(512, 2) void approx_scores(
    const float* __restrict__ s, const unsigned short* __restrict__ Wt,
    const float* __restrict__ W2, const float* __restrict__ b2,
    const float* __restrict__ avec, const float* __restrict__ bvec,
    unsigned short* __restrict__ ascu)
{
    int blk = blockIdx.x;              // 256 = b(4) x jt(4) x ic(16)
    int b   = blk >> 6;
    int jtb = ((blk >> 4) & 3) * 64;
    int i0  = (blk & 15) * 16;
    int t = threadIdx.x;
    int lane = t & 63;
    int w = __builtin_amdgcn_readfirstlane(t >> 6);
    int l15 = lane & 15, quad = lane >> 4;

    __shared__ __align__(16) short Pl[2][64 * 128];
    __shared__ __align__(16) float si_all[16][D_];
    __shared__ float partial[2][8][64];

    const float* sB = s + (size_t)b * N_ * D_;

    {
        int ii = t >> 5, dq = t & 31;
        *(float4*)&si_all[ii][dq * 4] =
            *(const float4*)(sB + (size_t)(i0 + ii) * D_ + dq * 4);
    }

    short8 Wreg[2][4];
    #pragma unroll
    for (int mi = 0; mi < 2; ++mi)
        #pragma unroll
        for (int dk = 0; dk < 4; ++dk)
            Wreg[mi][dk] = *(const short8*)(
                Wt + (size_t)(w * 32 + mi * 16 + l15) * D_ + dk * 32 + quad * 8);
    float bvr[2][4][4];
    float w2r[2][4];
    #pragma unroll
    for (int mi = 0; mi < 2; ++mi) {
        int hq = w * 32 + mi * 16 + quad * 4;
        #pragma unroll
        for (int r = 0; r < 4; ++r)
            w2r[mi][r] = W2[hq + r];
        #pragma unroll
        for (int nj = 0; nj < 4; ++nj)
            #pragma unroll
            for (int r = 0; r < 4; ++r)
                bvr[mi][nj][r] = bvec[((size_t)(b * N_ + jtb + nj * 16 + l15)) * H_
                                      + hq + r];
    }
    float b2v = b2[0];
    __syncthreads();

    {
        int row = t >> 3, seg = t & 7;
        const float* sj = sB + (size_t)(jtb + row) * D_ + seg * 16;
        float4 a0 = ((const float4*)sj)[0], a1 = ((const float4*)sj)[1];
        float4 a2 = ((const float4*)sj)[2], a3 = ((const float4*)sj)[3];
        const float* si = &si_all[0][seg * 16];
        float4 s0 = ((const float4*)si)[0], s1 = ((const float4*)si)[1];
        float4 s2 = ((const float4*)si)[2], s3 = ((const float4*)si)[3];
        uint4 v0, v1;
        v0.x = pk2(a0.x * s0.x, a0.y * s0.y); v0.y = pk2(a0.z * s0.z, a0.w * s0.w);
        v0.z = pk2(a1.x * s1.x, a1.y * s1.y); v0.w = pk2(a1.z * s1.z, a1.w * s1.w);
        v1.x = pk2(a2.x * s2.x, a2.y * s2.y); v1.y = pk2(a2.z * s2.z, a2.w * s2.w);
        v1.z = pk2(a3.x * s3.x, a3.y * s3.y); v1.w = pk2(a3.z * s3.z, a3.w * s3.w);
        int pc0 = (seg * 2) ^ (row & 15), pc1 = (seg * 2 + 1) ^ (row & 15);
        *(uint4*)&Pl[0][row * 128 + pc0 * 8] = v0;
        *(uint4*)&Pl[0][row * 128 + pc1 * 8] = v1;
    }
    __syncthreads();

    #pragma unroll 1
    for (int i = 0; i < 16; ++i) {
        int cur = i & 1;
        if (w == 0 && i > 0) {
            float sum = b2v;
            #pragma unroll
            for (int ww = 0; ww < 8; ++ww) sum += partial[(i - 1) & 1][ww][lane];
            ascu[(size_t)(b * N_ + i0 + i - 1) * N_ + jtb + lane] = f2bf(sum);
        }
        float avc[2][4];
        #pragma unroll
        for (int mi = 0; mi < 2; ++mi) {
            int hq = w * 32 + mi * 16 + quad * 4;
            #pragma unroll
            for (int r = 0; r < 4; ++r)
                avc[mi][r] = avec[(size_t)(b * N_ + i0 + i) * H_ + hq + r];
        }
        f32x4 acc[2][4];
        #pragma unroll
        for (int mi = 0; mi < 2; ++mi)
            #pragma unroll
            for (int nj = 0; nj < 4; ++nj)
                acc[mi][nj] = (f32x4){0.f, 0.f, 0.f, 0.f};
        #pragma unroll
        for (int dk = 0; dk < 4; ++dk) {
            short8 Pf[4];
            #pragma unroll
            for (int nj = 0; nj < 4; ++nj) {
                int pcc = (dk * 4 + quad) ^ l15;
                Pf[nj] = *(const short8*)&Pl[cur][(nj * 16 + l15) * 128 + pcc * 8];
            }
            #pragma unroll
            for (int nj = 0; nj < 4; ++nj)
                #pragma unroll
                for (int mi = 0; mi < 2; ++mi)
                    acc[mi][nj] = __builtin_amdgcn_mfma_f32_16x16x32_bf16(
                        Wreg[mi][dk], Pf[nj], acc[mi][nj], 0, 0, 0);
        }
        if (i < 15) {
            int row = t >> 3, seg = t & 7;
            const float* sj = sB + (size_t)(jtb + row) * D_ + seg * 16;
            float4 a0 = ((const float4*)sj)[0], a1 = ((const float4*)sj)[1];
            float4 a2 = ((const float4*)sj)[2], a3 = ((const float4*)sj)[3];
            const float* si = &si_all[i + 1][seg * 16];
            float4 s0 = ((const float4*)si)[0], s1 = ((const float4*)si)[1];
            float4 s2 = ((const float4*)si)[2], s3 = ((const float4*)si)[3];
            uint4 v0, v1;
            v0.x = pk2(a0.x * s0.x, a0.y * s0.y); v0.y = pk2(a0.z * s0.z, a0.w * s0.w);
            v0.z = pk2(a1.x * s1.x, a1.y * s1.y); v0.w = pk2(a1.z * s1.z, a1.w * s1.w);
            v1.x = pk2(a2.x * s2.x, a2.y * s2.y); v1.y = pk2(a2.z * s2.z, a2.w * s2.w);
            v1.z = pk2(a3.x * s3.x, a3.y * s3.y); v1.w = pk2(a3.z * s3.z, a3.w * s3.w);
            int pc0 = (seg * 2) ^ (row & 15), pc1 = (seg * 2 + 1) ^ (row & 15);
            *(uint4*)&Pl[cur ^ 1][row * 128 + pc0 * 8] = v0;
            *(uint4*)&Pl[cur ^ 1][row * 128 + pc1 * 8] = v1;
        }
        float rs[4];
        #pragma unroll
        for (int nj = 0; nj < 4; ++nj) rs[nj] = 0.f;
        #pragma unroll
        for (int mi = 0; mi < 2; ++mi)
            #pragma unroll
            for (int nj = 0; nj < 4; ++nj)
                #pragma unroll
                for (int r = 0; r < 4; ++r) {
                    float z = acc[mi][nj][r] + avc[mi][r] + bvr[mi][nj][r];
                    rs[nj] = fmaf(fmaxf(z, 0.f), w2r[mi][r], rs[nj]);
                }
        #pragma unroll
        for (int nj = 0; nj < 4; ++nj) {
            rs[nj] += __shfl_xor(rs[nj], 16);
            rs[nj] += __shfl_xor(rs[nj], 32);
        }
        float v = (quad == 0) ? rs[0] : (quad == 1) ? rs[1] : (quad == 2) ? rs[2] : rs[3];
        partial[cur][w][lane] = v;
        __syncthreads();
    }
    if (w == 0) {
        float sum = b2v;
        #pragma unroll
        for (int ww = 0; ww < 8; ++ww) sum += partial[15 & 1][ww][lane];
        ascu[(size_t)(b * N_ + i0 + 15) * N_ + jtb + lane] = f2bf(sum);
    }
}

// K2 v9: v8 with 512 threads (8 waves/CU) — R20 showed v8's counters were
// clean (74K conflicts, no spill) but Occupancy=10%: 256 blocks x 4 waves =
// 1 block/CU with nothing to hide ds_read latency (45 us vs ~13 us model).
// Thread tile halves to (cg 4 cands, rr, hg -> 8 h): acc[4][8]=32 regs,
// ~60 live — matches the 512-thr allocator's preferred 56-64 fit WITHOUT
// needing more (previous 512-thr spills were ~100-reg kernels).
#define DC8 8
__global__ __launch_bounds__(512) void finalize_kernel(
    const float* __restrict__ s, const float* __restrict__ W1,
    const float* __restrict__ W2, const float* __restrict__ b2,
    const float* __restrict__ avec, const float* __restrict__ bvec,
    const unsigned short* __restrict__ ascu,
    float* __restrict__ ctx, float* __restrict__ gate, float* __restrict__ w)
{
    int bi0 = blockIdx.x * 4;          // 256 blocks, 4 rows each
    int b = bi0 >> 8;
    int t = threadIdx.x;               // 0..511

    __shared__ float asc[4][N_];                     // 4 KB
    __shared__ int cand[4][16];
    __shared__ __align__(16) float Pt[D_ * 64];      // 32 KB, addr d*64+rr*16+c
    __shared__ __align__(16) float Wl[2][DC8 * H_];  // 16 KB DMA dbuf
    __shared__ float part[4][16][33];                // 8.4 KB
    __shared__ float rsc[4][16];
    __shared__ int sel8[4][8];

    // --- load approx scores: 2 per thread ---
    for (int e = t; e < 1024; e += 512) {
        int r = e >> 8, jj = e & 255;
        asc[r][jj] = bf2f(ascu[(size_t)(bi0 + r) * N_ + jj]);
    }
    __syncthreads();

    // --- rank-select top-16: 128 threads per row, 2 j's each ---
    {
        int r = t >> 7, lj = t & 127;
        float my[2]; int rk[2];
        #pragma unroll
        for (int m = 0; m < 2; ++m) { my[m] = asc[r][m * 128 + lj]; rk[m] = 0; }
        #pragma unroll 4
        for (int j2 = 0; j2 < N_; ++j2) {
            float o = asc[r][j2];
            #pragma unroll
            for (int m = 0; m < 2; ++m) {
                int jm = m * 128 + lj;
                rk[m] += (o > my[m]) || (o == my[m] && j2 < jm);
            }
        }
        #pragma unroll
        for (int m = 0; m < 2; ++m)
            if (rk[m] < 16) cand[r][rk[m]] = m * 128 + lj;
    }
    __syncthreads();

    const float* Wc = W1 + (size_t)2 * D_ * H_;      // W1c[d][h]

    // issue async DMA of W chunk 0 (8 KB = 512 x 16 B; 1 slot/thread)
    gld_lds16(Wc + t * 4, &Wl[0][t * 4]);

    // --- build Pt: Pt[d*64 + rr*16 + c] = s_i[d]*s_j[d] ---
    for (int e = t; e < 2048; e += 512) {
        int rr = e >> 9, c = e & 15, dq = (e >> 4) & 31;
        int j = cand[rr][c];
        float4 sj = *(const float4*)(s + ((size_t)(b * N_ + j)) * D_ + dq * 4);
        float4 si = *(const float4*)(s + ((size_t)(bi0 + rr)) * D_ + dq * 4);
        int base = (dq * 4) * 64 + rr * 16 + c;
        Pt[base + 0 * 64] = si.x * sj.x;
        Pt[base + 1 * 64] = si.y * sj.y;
        Pt[base + 2 * 64] = si.z * sj.z;
        Pt[base + 3 * 64] = si.w * sj.w;
    }

    // --- acc init: exact fp32 a_i[h] + b_j[h] for 4 cands x 8 h ---
    int cg = t & 3, rr = (t >> 2) & 3;
    int hg = t >> 4;                    // 0..31, 8 h each
    int h0 = hg * 8;
    float acc[4][8];
    {
        const float* av = avec + (size_t)(bi0 + rr) * H_ + h0;
        float4 av4[2];
        av4[0] = *(const float4*)(av);
        av4[1] = *(const float4*)(av + 4);
        #pragma unroll
        for (int cc = 0; cc < 4; ++cc) {
            int j = cand[rr][cg * 4 + cc];
            const float* bv = bvec + ((size_t)(b * N_ + j)) * H_ + h0;
            float4 b40 = *(const float4*)(bv);
            float4 b41 = *(const float4*)(bv + 4);
            acc[cc][0] = av4[0].x + b40.x;
            acc[cc][1] = av4[0].y + b40.y;
            acc[cc][2] = av4[0].z + b40.z;
            acc[cc][3] = av4[0].w + b40.w;
            acc[cc][4] = av4[1].x + b41.x;
            acc[cc][5] = av4[1].y + b41.y;
            acc[cc][6] = av4[1].z + b41.z;
            acc[cc][7] = av4[1].w + b41.w;
        }
    }
    __syncthreads();   // drains chunk-0 DMA + Pt writes

    // --- K-chunked GEMM (16 chunks of 8 d), async double-buffered W ---
    int pvoff = rr * 16 + cg * 4;
    #pragma unroll 1
    for (int ch = 0; ch < 16; ++ch) {
        int cur = ch & 1;
        if (ch < 15) {
            const float* src = Wc + (size_t)(ch + 1) * DC8 * H_;
            gld_lds16(src + t * 4, &Wl[cur ^ 1][t * 4]);
        }
        int d0 = ch * DC8;
        #pragma unroll
        for (int d = 0; d < DC8; ++d) {
            float4 pv = *(const float4*)&Pt[(d0 + d) * 64 + pvoff];
            float wv[8];
            *(float4*)&wv[0] = *(const float4*)&Wl[cur][d * H_ + h0];
            *(float4*)&wv[4] = *(const float4*)&Wl[cur][d * H_ + h0 + 4];
            #pragma unroll
            for (int m = 0; m < 8; ++m) {
                acc[0][m] = fmaf(pv.x, wv[m], acc[0][m]);
                acc[1][m] = fmaf(pv.y, wv[m], acc[1][m]);
                acc[2][m] = fmaf(pv.z, wv[m], acc[2][m]);
                acc[3][m] = fmaf(pv.w, wv[m], acc[3][m]);
            }
        }
        __syncthreads();
    }

    // --- epilogue: relu * W2 partial per (r, cand), reduce over 32 hg ---
    {
        float w2v[8];
        *(float4*)&w2v[0] = *(const float4*)(W2 + h0);
        *(float4*)&w2v[4] = *(const float4*)(W2 + h0 + 4);
        #pragma unroll
        for (int cc = 0; cc < 4; ++cc) {
            float sc = 0.f;
            #pragma unroll
            for (int m = 0; m < 8; ++m)
                sc = fmaf(fmaxf(acc[cc][m], 0.f), w2v[m], sc);
            part[rr][cg * 4 + cc][hg] = sc;
        }
    }
    __syncthreads();
    if (t < 64) {
        int r2 = t >> 4, c2 = t & 15;
        float sum = b2[0];
        #pragma unroll
        for (int m = 0; m < 32; ++m) sum += part[r2][c2][m];
        rsc[r2][c2] = sum;
    }
    __syncthreads();

    // top-8 among 16 exact scores, tiebreak smaller original index
    if (t < 64) {
        int r2 = t >> 4, c2 = t & 15;
        float my = rsc[r2][c2]; int myj = cand[r2][c2];
        int rank = 0;
        #pragma unroll
        for (int c3 = 0; c3 < 16; ++c3) {
            float o = rsc[r2][c3]; int oj = cand[r2][c3];
            rank += (o > my) || (o == my && oj < myj);
        }
        if (rank < 8) sel8[r2][rank] = myj;
    }
    __syncthreads();

    // gate / w: 4 rows x 256 j, 2 per thread
    for (int e = t; e < 1024; e += 512) {
        int r2 = e >> 8, jj = e & 255;
        float gv = 0.f;
        #pragma unroll
        for (int m = 0; m < 8; ++m)
            gv = (jj == sel8[r2][m]) ? 1.f : gv;
        gate[(size_t)(bi0 + r2) * N_ + jj] = gv;
        w[(size_t)(bi0 + r2) * N_ + jj]    = gv * 0.125f;
    }
    // ctx: 4 rows x 128 d, 1 per thread
    {
        int r2 = t >> 7, d = t & 127;
        float a = 0.f;
        #pragma unroll
        for (int m = 0; m < 8; ++m)
            a += s[((size_t)(b * N_ + sel8[r2][m])) * D_ + d];
        ctx[(size_t)(bi0 + r2) * D_ + d] = a * 0.125f;
    }
}

extern "C" void kernel_launch(void* const* d_in, const int* in_sizes, int n_in,
                              void* d_out, int out_size, void* d_ws, size_t ws_size,
                              hipStream_t stream)
{
    const float* s  = (const float*)d_in[0];
    const float* W1 = (const float*)d_in[1];
    const float* b1 = (const float*)d_in[2];
    const float* W2 = (const float*)d_in[3];
    const float* b2 = (const float*)d_in[4];

    float* avec = (float*)d_ws;                                           // 262144 f
    float* bvec = avec + (size_t)B_ * N_ * H_;                            // 262144 f
    unsigned short* ascu = (unsigned short*)(bvec + (size_t)B_ * N_ * H_);// 262144 us
    unsigned short* Wtu  = ascu + (size_t)B_ * N_ * N_;                   // 32768 us

    float* ctx  = (float*)d_out;
    float* gate = ctx + (size_t)B_ * N_ * D_;
    float* wout = gate + (size_t)B_ * N_ * N_;

    pre_kernel<<<640, 256, 0, stream>>>(s, W1, b1, avec, bvec, Wtu);
    approx_scores<<<256, 512, 0, stream>>>(s, Wtu, W2, b2, avec, bvec, ascu);
    finalize_kernel<<<B_ * N_ / 4, 512, 0, stream>>>(s, W1, W2, b2, avec, bvec, ascu,
                                                     ctx, gate, wout);
}

// Round 22
// 129.673 us; speedup vs baseline: 1.1407x; 1.0533x over previous
//
#include <hip/hip_runtime.h>
#include <hip/hip_bf16.h>
#include <math.h>

#define B_ 4
#define N_ 256
#define D_ 128
#define H_ 256
#define K_ 8

typedef __attribute__((ext_vector_type(8))) short short8;
typedef __attribute__((ext_vector_type(4))) float f32x4;

__device__ __forceinline__ unsigned short f2bf(float x) {
    union { __hip_bfloat16 h; unsigned short s; } u;
    u.h = __float2bfloat16(x);
    return u.s;
}
__device__ __forceinline__ float bf2f(unsigned short b) {
    unsigned v = ((unsigned)b) << 16;
    return __builtin_bit_cast(float, v);
}
__device__ __forceinline__ unsigned pk2(float x, float y) {
    union { __hip_bfloat162 h; unsigned u; } c;
    c.h = __float22bfloat162_rn(float2{x, y});
    return c.u;
}
// async global->LDS, 16 B per lane (m97-verified width); no VGPR round-trip
__device__ __forceinline__ void gld_lds16(const float* g, float* l) {
    __builtin_amdgcn_global_load_lds(
        (const __attribute__((address_space(1))) void*)g,
        (__attribute__((address_space(3))) void*)l, 16, 0, 0);
}

// K0 v2 (unchanged).
__global__ __launch_bounds__(256) void pre_kernel(
    const float* __restrict__ s, const float* __restrict__ W1,
    const float* __restrict__ b1,
    float* __restrict__ avec, float* __restrict__ bvec,
    unsigned short* __restrict__ Wt)
{
    int blk = blockIdx.x;
    int t = threadIdx.x;
    if (blk < 512) {
        int bi0 = blk * 2;
        __shared__ float s2[2][D_];
        {
            int r = t >> 7, d = t & 127;
            s2[r][d] = s[(size_t)(bi0 + r) * D_ + d];
        }
        __syncthreads();
        float aA0 = b1[t], aA1 = aA0, aB0 = 0.f, aB1 = 0.f;
        const float* W1a = W1 + t;
        const float* W1b = W1 + (size_t)D_ * H_ + t;
        #pragma unroll 8
        for (int d = 0; d < D_; ++d) {
            float wa = W1a[(size_t)d * H_];
            float wb = W1b[(size_t)d * H_];
            float s0 = s2[0][d], s1 = s2[1][d];
            aA0 = fmaf(s0, wa, aA0);
            aA1 = fmaf(s1, wa, aA1);
            aB0 = fmaf(s0, wb, aB0);
            aB1 = fmaf(s1, wb, aB1);
        }
        avec[(size_t)bi0 * H_ + t]       = aA0;
        avec[(size_t)(bi0 + 1) * H_ + t] = aA1;
        bvec[(size_t)bi0 * H_ + t]       = aB0;
        bvec[(size_t)(bi0 + 1) * H_ + t] = aB1;
    } else {
        int e = (blk - 512) * 256 + t;
        int h = e >> 7, d = e & 127;
        Wt[e] = f2bf(W1[(size_t)(2 * D_ + d) * H_ + h]);
    }
}

// K1 v6: j-split instead of R17's failed i-split. Block = (b, jt of 32 j,
// ic of 16 i) -> 512 blocks = 2 co-resident blocks/CU (LDS 26 KB), while the
// i-amortization (Wreg/avc per-i costs over 16 i) is UNCHANGED — bvr and
// MFMA work halve proportionally with the block, so prologue-per-work is
// constant. Only Wreg/si_all become 2x-redundant L2 reads (trivial).
__global__ __launch_bounds__(512, 2) void approx_scores(
    const float* __restrict__ s, const unsigned short* __restrict__ Wt,
    const float* __restrict__ W2, const float* __restrict__ b2,
    const float* __restrict__ avec, const float* __restrict__ bvec,
    unsigned short* __restrict__ ascu)
{
    int blk = blockIdx.x;              // 512 = b(4) x jt(8) x ic(16)
    int b   = blk >> 7;
    int jtb = ((blk >> 4) & 7) * 32;
    int i0  = (blk & 15) * 16;
    int t = threadIdx.x;
    int lane = t & 63;
    int w = __builtin_amdgcn_readfirstlane(t >> 6);    // wave 0..7 -> 32-h slice
    int l15 = lane & 15, quad = lane >> 4;

    __shared__ __align__(16) short Pl[2][32 * 128];    // 16 KB (dbuf)
    __shared__ __align__(16) float si_all[16][D_];     // 8 KB
    __shared__ float partial[2][8][32];                // 2 KB

    const float* sB = s + (size_t)b * N_ * D_;

    {
        int ii = t >> 5, dq = t & 31;
        *(float4*)&si_all[ii][dq * 4] =
            *(const float4*)(sB + (size_t)(i0 + ii) * D_ + dq * 4);
    }

    short8 Wreg[2][4];
    #pragma unroll
    for (int mi = 0; mi < 2; ++mi)
        #pragma unroll
        for (int dk = 0; dk < 4; ++dk)
            Wreg[mi][dk] = *(const short8*)(
                Wt + (size_t)(w * 32 + mi * 16 + l15) * D_ + dk * 32 + quad * 8);
    float bvr[2][2][4];
    float w2r[2][4];
    #pragma unroll
    for (int mi = 0; mi < 2; ++mi) {
        int hq = w * 32 + mi * 16 + quad * 4;
        #pragma unroll
        for (int r = 0; r < 4; ++r)
            w2r[mi][r] = W2[hq + r];
        #pragma unroll
        for (int nj = 0; nj < 2; ++nj)
            #pragma unroll
            for (int r = 0; r < 4; ++r)
                bvr[mi][nj][r] = bvec[((size_t)(b * N_ + jtb + nj * 16 + l15)) * H_
                                      + hq + r];
    }
    float b2v = b2[0];
    __syncthreads();                   // si_all ready

    // ---- stage P[0]: 32 rows x 128 d; thread = (row = t>>4, seg = t&15) ----
    {
        int row = t >> 4, seg = t & 15;
        const float* sj = sB + (size_t)(jtb + row) * D_ + seg * 8;
        float4 a0 = ((const float4*)sj)[0], a1 = ((const float4*)sj)[1];
        const float* si = &si_all[0][seg * 8];
        float4 s0 = ((const float4*)si)[0], s1 = ((const float4*)si)[1];
        uint4 v;
        v.x = pk2(a0.x * s0.x, a0.y * s0.y);
        v.y = pk2(a0.z * s0.z, a0.w * s0.w);
        v.z = pk2(a1.x * s1.x, a1.y * s1.y);
        v.w = pk2(a1.z * s1.z, a1.w * s1.w);
        int pc = seg ^ (row & 15);
        *(uint4*)&Pl[0][row * 128 + pc * 8] = v;
    }
    __syncthreads();

    #pragma unroll 1
    for (int i = 0; i < 16; ++i) {
        int cur = i & 1;
        if (w == 0 && lane < 32 && i > 0) {
            float sum = b2v;
            #pragma unroll
            for (int ww = 0; ww < 8; ++ww) sum += partial[(i - 1) & 1][ww][lane];
            ascu[(size_t)(b * N_ + i0 + i - 1) * N_ + jtb + lane] = f2bf(sum);
        }
        float avc[2][4];
        #pragma unroll
        for (int mi = 0; mi < 2; ++mi) {
            int hq = w * 32 + mi * 16 + quad * 4;
            #pragma unroll
            for (int r = 0; r < 4; ++r)
                avc[mi][r] = avec[(size_t)(b * N_ + i0 + i) * H_ + hq + r];
        }
        f32x4 acc[2][2];
        #pragma unroll
        for (int mi = 0; mi < 2; ++mi)
            #pragma unroll
            for (int nj = 0; nj < 2; ++nj)
                acc[mi][nj] = (f32x4){0.f, 0.f, 0.f, 0.f};
        #pragma unroll
        for (int dk = 0; dk < 4; ++dk) {
            short8 Pf[2];
            #pragma unroll
            for (int nj = 0; nj < 2; ++nj) {
                int pcc = (dk * 4 + quad) ^ l15;
                Pf[nj] = *(const short8*)&Pl[cur][(nj * 16 + l15) * 128 + pcc * 8];
            }
            #pragma unroll
            for (int nj = 0; nj < 2; ++nj)
                #pragma unroll
                for (int mi = 0; mi < 2; ++mi)
                    acc[mi][nj] = __builtin_amdgcn_mfma_f32_16x16x32_bf16(
                        Wreg[mi][dk], Pf[nj], acc[mi][nj], 0, 0, 0);
        }
        if (i < 15) {
            int row = t >> 4, seg = t & 15;
            const float* sj = sB + (size_t)(jtb + row) * D_ + seg * 8;
            float4 a0 = ((const float4*)sj)[0], a1 = ((const float4*)sj)[1];
            const float* si = &si_all[i + 1][seg * 8];
            float4 s0 = ((const float4*)si)[0], s1 = ((const float4*)si)[1];
            uint4 v;
            v.x = pk2(a0.x * s0.x, a0.y * s0.y);
            v.y = pk2(a0.z * s0.z, a0.w * s0.w);
            v.z = pk2(a1.x * s1.x, a1.y * s1.y);
            v.w = pk2(a1.z * s1.z, a1.w * s1.w);
            int pc = seg ^ (row & 15);
            *(uint4*)&Pl[cur ^ 1][row * 128 + pc * 8] = v;
        }
        float rs[2];
        rs[0] = 0.f; rs[1] = 0.f;
        #pragma unroll
        for (int mi = 0; mi < 2; ++mi)
            #pragma unroll
            for (int nj = 0; nj < 2; ++nj)
                #pragma unroll
                for (int r = 0; r < 4; ++r) {
                    float z = acc[mi][nj][r] + avc[mi][r] + bvr[mi][nj][r];
                    rs[nj] = fmaf(fmaxf(z, 0.f), w2r[mi][r], rs[nj]);
                }
        #pragma unroll
        for (int nj = 0; nj < 2; ++nj) {
            rs[nj] += __shfl_xor(rs[nj], 16);
            rs[nj] += __shfl_xor(rs[nj], 32);
        }
        // lanes 0..31: j = quad*16 + l15 = lane, value rs[quad]
        if (lane < 32) {
            float v = (quad == 0) ? rs[0] : rs[1];
            partial[cur][w][lane] = v;
        }
        __syncthreads();
    }
    if (w == 0 && lane < 32) {
        float sum = b2v;
        #pragma unroll
        for (int ww = 0; ww < 8; ++ww) sum += partial[15 & 1][ww][lane];
        ascu[(size_t)(b * N_ + i0 + 15) * N_ + jtb + lane] = f2bf(sum);
    }
}

// K2 v9 (unchanged from R21 — passed, left top-5).
#define DC8 8
__global__ __launch_bounds__(512) void finalize_kernel(
    const float* __restrict__ s, const float* __restrict__ W1,
    const float* __restrict__ W2, const float* __restrict__ b2,
    const float* __restrict__ avec, const float* __restrict__ bvec,
    const unsigned short* __restrict__ ascu,
    float* __restrict__ ctx, float* __restrict__ gate, float* __restrict__ w)
{
    int bi0 = blockIdx.x * 4;          // 256 blocks, 4 rows each
    int b = bi0 >> 8;
    int t = threadIdx.x;               // 0..511

    __shared__ float asc[4][N_];
    __shared__ int cand[4][16];
    __shared__ __align__(16) float Pt[D_ * 64];
    __shared__ __align__(16) float Wl[2][DC8 * H_];
    __shared__ float part[4][16][33];
    __shared__ float rsc[4][16];
    __shared__ int sel8[4][8];

    for (int e = t; e < 1024; e += 512) {
        int r = e >> 8, jj = e & 255;
        asc[r][jj] = bf2f(ascu[(size_t)(bi0 + r) * N_ + jj]);
    }
    __syncthreads();

    {
        int r = t >> 7, lj = t & 127;
        float my[2]; int rk[2];
        #pragma unroll
        for (int m = 0; m < 2; ++m) { my[m] = asc[r][m * 128 + lj]; rk[m] = 0; }
        #pragma unroll 4
        for (int j2 = 0; j2 < N_; ++j2) {
            float o = asc[r][j2];
            #pragma unroll
            for (int m = 0; m < 2; ++m) {
                int jm = m * 128 + lj;
                rk[m] += (o > my[m]) || (o == my[m] && j2 < jm);
            }
        }
        #pragma unroll
        for (int m = 0; m < 2; ++m)
            if (rk[m] < 16) cand[r][rk[m]] = m * 128 + lj;
    }
    __syncthreads();

    const float* Wc = W1 + (size_t)2 * D_ * H_;

    gld_lds16(Wc + t * 4, &Wl[0][t * 4]);

    for (int e = t; e < 2048; e += 512) {
        int rr = e >> 9, c = e & 15, dq = (e >> 4) & 31;
        int j = cand[rr][c];
        float4 sj = *(const float4*)(s + ((size_t)(b * N_ + j)) * D_ + dq * 4);
        float4 si = *(const float4*)(s + ((size_t)(bi0 + rr)) * D_ + dq * 4);
        int base = (dq * 4) * 64 + rr * 16 + c;
        Pt[base + 0 * 64] = si.x * sj.x;
        Pt[base + 1 * 64] = si.y * sj.y;
        Pt[base + 2 * 64] = si.z * sj.z;
        Pt[base + 3 * 64] = si.w * sj.w;
    }

    int cg = t & 3, rr = (t >> 2) & 3;
    int hg = t >> 4;
    int h0 = hg * 8;
    float acc[4][8];
    {
        const float* av = avec + (size_t)(bi0 + rr) * H_ + h0;
        float4 av4[2];
        av4[0] = *(const float4*)(av);
        av4[1] = *(const float4*)(av + 4);
        #pragma unroll
        for (int cc = 0; cc < 4; ++cc) {
            int j = cand[rr][cg * 4 + cc];
            const float* bv = bvec + ((size_t)(b * N_ + j)) * H_ + h0;
            float4 b40 = *(const float4*)(bv);
            float4 b41 = *(const float4*)(bv + 4);
            acc[cc][0] = av4[0].x + b40.x;
            acc[cc][1] = av4[0].y + b40.y;
            acc[cc][2] = av4[0].z + b40.z;
            acc[cc][3] = av4[0].w + b40.w;
            acc[cc][4] = av4[1].x + b41.x;
            acc[cc][5] = av4[1].y + b41.y;
            acc[cc][6] = av4[1].z + b41.z;
            acc[cc][7] = av4[1].w + b41.w;
        }
    }
    __syncthreads();

    int pvoff = rr * 16 + cg * 4;
    #pragma unroll 1
    for (int ch = 0; ch < 16; ++ch) {
        int cur = ch & 1;
        if (ch < 15) {
            const float* src = Wc + (size_t)(ch + 1) * DC8 * H_;
            gld_lds16(src + t * 4, &Wl[cur ^ 1][t * 4]);
        }
        int d0 = ch * DC8;
        #pragma unroll
        for (int d = 0; d < DC8; ++d) {
            float4 pv = *(const float4*)&Pt[(d0 + d) * 64 + pvoff];
            float wv[8];
            *(float4*)&wv[0] = *(const float4*)&Wl[cur][d * H_ + h0];
            *(float4*)&wv[4] = *(const float4*)&Wl[cur][d * H_ + h0 + 4];
            #pragma unroll
            for (int m = 0; m < 8; ++m) {
                acc[0][m] = fmaf(pv.x, wv[m], acc[0][m]);
                acc[1][m] = fmaf(pv.y, wv[m], acc[1][m]);
                acc[2][m] = fmaf(pv.z, wv[m], acc[2][m]);
                acc[3][m] = fmaf(pv.w, wv[m], acc[3][m]);
            }
        }
        __syncthreads();
    }

    {
        float w2v[8];
        *(float4*)&w2v[0] = *(const float4*)(W2 + h0);
        *(float4*)&w2v[4] = *(const float4*)(W2 + h0 + 4);
        #pragma unroll
        for (int cc = 0; cc < 4; ++cc) {
            float sc = 0.f;
            #pragma unroll
            for (int m = 0; m < 8; ++m)
                sc = fmaf(fmaxf(acc[cc][m], 0.f), w2v[m], sc);
            part[rr][cg * 4 + cc][hg] = sc;
        }
    }
    __syncthreads();
    if (t < 64) {
        int r2 = t >> 4, c2 = t & 15;
        float sum = b2[0];
        #pragma unroll
        for (int m = 0; m < 32; ++m) sum += part[r2][c2][m];
        rsc[r2][c2] = sum;
    }
    __syncthreads();

    if (t < 64) {
        int r2 = t >> 4, c2 = t & 15;
        float my = rsc[r2][c2]; int myj = cand[r2][c2];
        int rank = 0;
        #pragma unroll
        for (int c3 = 0; c3 < 16; ++c3) {
            float o = rsc[r2][c3]; int oj = cand[r2][c3];
            rank += (o > my) || (o == my && oj < myj);
        }
        if (rank < 8) sel8[r2][rank] = myj;
    }
    __syncthreads();

    for (int e = t; e < 1024; e += 512) {
        int r2 = e >> 8, jj = e & 255;
        float gv = 0.f;
        #pragma unroll
        for (int m = 0; m < 8; ++m)
            gv = (jj == sel8[r2][m]) ? 1.f : gv;
        gate[(size_t)(bi0 + r2) * N_ + jj] = gv;
        w[(size_t)(bi0 + r2) * N_ + jj]    = gv * 0.125f;
    }
    {
        int r2 = t >> 7, d = t & 127;
        float a = 0.f;
        #pragma unroll
        for (int m = 0; m < 8; ++m)
            a += s[((size_t)(b * N_ + sel8[r2][m])) * D_ + d];
        ctx[(size_t)(bi0 + r2) * D_ + d] = a * 0.125f;
    }
}

extern "C" void kernel_launch(void* const* d_in, const int* in_sizes, int n_in,
                              void* d_out, int out_size, void* d_ws, size_t ws_size,
                              hipStream_t stream)
{
    const float* s  = (const float*)d_in[0];
    const float* W1 = (const float*)d_in[1];
    const float* b1 = (const float*)d_in[2];
    const float* W2 = (const float*)d_in[3];
    const float* b2 = (const float*)d_in[4];

    float* avec = (float*)d_ws;                                           // 262144 f
    float* bvec = avec + (size_t)B_ * N_ * H_;                            // 262144 f
    unsigned short* ascu = (unsigned short*)(bvec + (size_t)B_ * N_ * H_);// 262144 us
    unsigned short* Wtu  = ascu + (size_t)B_ * N_ * N_;                   // 32768 us

    float* ctx  = (float*)d_out;
    float* gate = ctx + (size_t)B_ * N_ * D_;
    float* wout = gate + (size_t)B_ * N_ * N_;

    pre_kernel<<<640, 256, 0, stream>>>(s, W1, b1, avec, bvec, Wtu);
    approx_scores<<<512, 512, 0, stream>>>(s, Wtu, W2, b2, avec, bvec, ascu);
    finalize_kernel<<<B_ * N_ / 4, 512, 0, stream>>>(s, W1, W2, b2, avec, bvec, ascu,
                                                     ctx, gate, wout);
}

// Round 24
// 129.259 us; speedup vs baseline: 1.1444x; 1.0032x over previous
//
#include <hip/hip_runtime.h>
#include <hip/hip_bf16.h>
#include <math.h>

#define B_ 4
#define N_ 256
#define D_ 128
#define H_ 256
#define K_ 8

typedef __attribute__((ext_vector_type(8))) short short8;
typedef __attribute__((ext_vector_type(4))) float f32x4;

__device__ __forceinline__ unsigned short f2bf(float x) {
    union { __hip_bfloat16 h; unsigned short s; } u;
    u.h = __float2bfloat16(x);
    return u.s;
}
__device__ __forceinline__ float bf2f(unsigned short b) {
    unsigned v = ((unsigned)b) << 16;
    return __builtin_bit_cast(float, v);
}
__device__ __forceinline__ unsigned pk2(float x, float y) {
    union { __hip_bfloat162 h; unsigned u; } c;
    c.h = __float22bfloat162_rn(float2{x, y});
    return c.u;
}
// async global->LDS, 16 B per lane (m97-verified width); no VGPR round-trip
__device__ __forceinline__ void gld_lds16(const float* g, float* l) {
    __builtin_amdgcn_global_load_lds(
        (const __attribute__((address_space(1))) void*)g,
        (__attribute__((address_space(3))) void*)l, 16, 0, 0);
}

// K0 v2 (unchanged).
__global__ __launch_bounds__(256) void pre_kernel(
    const float* __restrict__ s, const float* __restrict__ W1,
    const float* __restrict__ b1,
    float* __restrict__ avec, float* __restrict__ bvec,
    unsigned short* __restrict__ Wt)
{
    int blk = blockIdx.x;
    int t = threadIdx.x;
    if (blk < 512) {
        int bi0 = blk * 2;
        __shared__ float s2[2][D_];
        {
            int r = t >> 7, d = t & 127;
            s2[r][d] = s[(size_t)(bi0 + r) * D_ + d];
        }
        __syncthreads();
        float aA0 = b1[t], aA1 = aA0, aB0 = 0.f, aB1 = 0.f;
        const float* W1a = W1 + t;
        const float* W1b = W1 + (size_t)D_ * H_ + t;
        #pragma unroll 8
        for (int d = 0; d < D_; ++d) {
            float wa = W1a[(size_t)d * H_];
            float wb = W1b[(size_t)d * H_];
            float s0 = s2[0][d], s1 = s2[1][d];
            aA0 = fmaf(s0, wa, aA0);
            aA1 = fmaf(s1, wa, aA1);
            aB0 = fmaf(s0, wb, aB0);
            aB1 = fmaf(s1, wb, aB1);
        }
        avec[(size_t)bi0 * H_ + t]       = aA0;
        avec[(size_t)(bi0 + 1) * H_ + t] = aA1;
        bvec[(size_t)bi0 * H_ + t]       = aB0;
        bvec[(size_t)(bi0 + 1) * H_ + t] = aB1;
    } else {
        int e = (blk - 512) * 256 + t;
        int h = e >> 7, d = e & 127;
        Wt[e] = f2bf(W1[(size_t)(2 * D_ + d) * H_ + h]);
    }
}

// K1 v6 (unchanged — R22's win: j-split, 512 blocks, 2 blocks/CU).
__global__ __launch_bounds__(512, 2) void approx_scores(
    const float* __restrict__ s, const unsigned short* __restrict__ Wt,
    const float* __restrict__ W2, const float* __restrict__ b2,
    const float* __restrict__ avec, const float* __restrict__ bvec,
    unsigned short* __restrict__ ascu)
{
    int blk = blockIdx.x;              // 512 = b(4) x jt(8) x ic(16)
    int b   = blk >> 7;
    int jtb = ((blk >> 4) & 7) * 32;
    int i0  = (blk & 15) * 16;
    int t = threadIdx.x;
    int lane = t & 63;
    int w = __builtin_amdgcn_readfirstlane(t >> 6);    // wave 0..7 -> 32-h slice
    int l15 = lane & 15, quad = lane >> 4;

    __shared__ __align__(16) short Pl[2][32 * 128];    // 16 KB (dbuf)
    __shared__ __align__(16) float si_all[16][D_];     // 8 KB
    __shared__ float partial[2][8][32];                // 2 KB

    const float* sB = s + (size_t)b * N_ * D_;

    {
        int ii = t >> 5, dq = t & 31;
        *(float4*)&si_all[ii][dq * 4] =
            *(const float4*)(sB + (size_t)(i0 + ii) * D_ + dq * 4);
    }

    short8 Wreg[2][4];
    #pragma unroll
    for (int mi = 0; mi < 2; ++mi)
        #pragma unroll
        for (int dk = 0; dk < 4; ++dk)
            Wreg[mi][dk] = *(const short8*)(
                Wt + (size_t)(w * 32 + mi * 16 + l15) * D_ + dk * 32 + quad * 8);
    float bvr[2][2][4];
    float w2r[2][4];
    #pragma unroll
    for (int mi = 0; mi < 2; ++mi) {
        int hq = w * 32 + mi * 16 + quad * 4;
        #pragma unroll
        for (int r = 0; r < 4; ++r)
            w2r[mi][r] = W2[hq + r];
        #pragma unroll
        for (int nj = 0; nj < 2; ++nj)
            #pragma unroll
            for (int r = 0; r < 4; ++r)
                bvr[mi][nj][r] = bvec[((size_t)(b * N_ + jtb + nj * 16 + l15)) * H_
                                      + hq + r];
    }
    float b2v = b2[0];
    __syncthreads();                   // si_all ready

    {
        int row = t >> 4, seg = t & 15;
        const float* sj = sB + (size_t)(jtb + row) * D_ + seg * 8;
        float4 a0 = ((const float4*)sj)[0], a1 = ((const float4*)sj)[1];
        const float* si = &si_all[0][seg * 8];
        float4 s0 = ((const float4*)si)[0], s1 = ((const float4*)si)[1];
        uint4 v;
        v.x = pk2(a0.x * s0.x, a0.y * s0.y);
        v.y = pk2(a0.z * s0.z, a0.w * s0.w);
        v.z = pk2(a1.x * s1.x, a1.y * s1.y);
        v.w = pk2(a1.z * s1.z, a1.w * s1.w);
        int pc = seg ^ (row & 15);
        *(uint4*)&Pl[0][row * 128 + pc * 8] = v;
    }
    __syncthreads();

    #pragma unroll 1
    for (int i = 0; i < 16; ++i) {
        int cur = i & 1;
        if (w == 0 && lane < 32 && i > 0) {
            float sum = b2v;
            #pragma unroll
            for (int ww = 0; ww < 8; ++ww) sum += partial[(i - 1) & 1][ww][lane];
            ascu[(size_t)(b * N_ + i0 + i - 1) * N_ + jtb + lane] = f2bf(sum);
        }
        float avc[2][4];
        #pragma unroll
        for (int mi = 0; mi < 2; ++mi) {
            int hq = w * 32 + mi * 16 + quad * 4;
            #pragma unroll
            for (int r = 0; r < 4; ++r)
                avc[mi][r] = avec[(size_t)(b * N_ + i0 + i) * H_ + hq + r];
        }
        f32x4 acc[2][2];
        #pragma unroll
        for (int mi = 0; mi < 2; ++mi)
            #pragma unroll
            for (int nj = 0; nj < 2; ++nj)
                acc[mi][nj] = (f32x4){0.f, 0.f, 0.f, 0.f};
        #pragma unroll
        for (int dk = 0; dk < 4; ++dk) {
            short8 Pf[2];
            #pragma unroll
            for (int nj = 0; nj < 2; ++nj) {
                int pcc = (dk * 4 + quad) ^ l15;
                Pf[nj] = *(const short8*)&Pl[cur][(nj * 16 + l15) * 128 + pcc * 8];
            }
            #pragma unroll
            for (int nj = 0; nj < 2; ++nj)
                #pragma unroll
                for (int mi = 0; mi < 2; ++mi)
                    acc[mi][nj] = __builtin_amdgcn_mfma_f32_16x16x32_bf16(
                        Wreg[mi][dk], Pf[nj], acc[mi][nj], 0, 0, 0);
        }
        if (i < 15) {
            int row = t >> 4, seg = t & 15;
            const float* sj = sB + (size_t)(jtb + row) * D_ + seg * 8;
            float4 a0 = ((const float4*)sj)[0], a1 = ((const float4*)sj)[1];
            const float* si = &si_all[i + 1][seg * 8];
            float4 s0 = ((const float4*)si)[0], s1 = ((const float4*)si)[1];
            uint4 v;
            v.x = pk2(a0.x * s0.x, a0.y * s0.y);
            v.y = pk2(a0.z * s0.z, a0.w * s0.w);
            v.z = pk2(a1.x * s1.x, a1.y * s1.y);
            v.w = pk2(a1.z * s1.z, a1.w * s1.w);
            int pc = seg ^ (row & 15);
            *(uint4*)&Pl[cur ^ 1][row * 128 + pc * 8] = v;
        }
        float rs[2];
        rs[0] = 0.f; rs[1] = 0.f;
        #pragma unroll
        for (int mi = 0; mi < 2; ++mi)
            #pragma unroll
            for (int nj = 0; nj < 2; ++nj)
                #pragma unroll
                for (int r = 0; r < 4; ++r) {
                    float z = acc[mi][nj][r] + avc[mi][r] + bvr[mi][nj][r];
                    rs[nj] = fmaf(fmaxf(z, 0.f), w2r[mi][r], rs[nj]);
                }
        #pragma unroll
        for (int nj = 0; nj < 2; ++nj) {
            rs[nj] += __shfl_xor(rs[nj], 16);
            rs[nj] += __shfl_xor(rs[nj], 32);
        }
        if (lane < 32) {
            float v = (quad == 0) ? rs[0] : rs[1];
            partial[cur][w][lane] = v;
        }
        __syncthreads();
    }
    if (w == 0 && lane < 32) {
        float sum = b2v;
        #pragma unroll
        for (int ww = 0; ww < 8; ++ww) sum += partial[15 & 1][ww][lane];
        ascu[(size_t)(b * N_ + i0 + 15) * N_ + jtb + lane] = f2bf(sum);
    }
}

// K2 v10: v9 resized for co-residency. 2 rows/block x 512 blocks x 256 thr;
// thread = (cg 4 cands, rr 0..1, hg -> 8 h), acc[4][8]=32 regs (~60 live,
// the 256-thr allocator's proven spill-free regime). LDS ~39 KB -> 4
// blocks/CU capacity, 2 resident: each chunk barrier is covered by the
// other block's waves (v9 was 61 KB -> thin residency, 40 us vs 15 us model).
// pv: 8 distinct float4/wave tiling all 32 banks (free); wv 2-way (free).
#define DC8 8
__global__ __launch_bounds__(256) void finalize_kernel(
    const float* __restrict__ s, const float* __restrict__ W1,
    const float* __restrict__ W2, const float* __restrict__ b2,
    const float* __restrict__ avec, const float* __restrict__ bvec,
    const unsigned short* __restrict__ ascu,
    float* __restrict__ ctx, float* __restrict__ gate, float* __restrict__ w)
{
    int bi0 = blockIdx.x * 2;          // 512 blocks, 2 rows each
    int b = bi0 >> 8;
    int t = threadIdx.x;               // 0..255

    __shared__ float asc[2][N_];                     // 2 KB
    __shared__ int cand[2][16];
    __shared__ __align__(16) float Pt[D_ * 32];      // 16 KB, addr d*32+rr*16+c
    __shared__ __align__(16) float Wl[2][DC8 * H_];  // 16 KB DMA dbuf
    __shared__ float part[2][16][33];                // 4.2 KB
    __shared__ float rsc[2][16];
    __shared__ int sel8[2][8];

    // --- load approx scores: 2 per thread ---
    for (int e = t; e < 512; e += 256) {
        int r = e >> 8, jj = e & 255;
        asc[r][jj] = bf2f(ascu[(size_t)(bi0 + r) * N_ + jj]);
    }
    __syncthreads();

    // --- rank-select top-16: 128 threads per row, 2 j's each ---
    {
        int r = t >> 7, lj = t & 127;
        float my[2]; int rk[2];
        #pragma unroll
        for (int m = 0; m < 2; ++m) { my[m] = asc[r][m * 128 + lj]; rk[m] = 0; }
        #pragma unroll 4
        for (int j2 = 0; j2 < N_; ++j2) {
            float o = asc[r][j2];
            #pragma unroll
            for (int m = 0; m < 2; ++m) {
                int jm = m * 128 + lj;
                rk[m] += (o > my[m]) || (o == my[m] && j2 < jm);
            }
        }
        #pragma unroll
        for (int m = 0; m < 2; ++m)
            if (rk[m] < 16) cand[r][rk[m]] = m * 128 + lj;
    }
    __syncthreads();

    const float* Wc = W1 + (size_t)2 * D_ * H_;      // W1c[d][h]

    // issue async DMA of W chunk 0 (8 KB = 512 x 16 B; 2 slots/thread)
    #pragma unroll
    for (int k = 0; k < 2; ++k) {
        int slot = t + 256 * k;
        gld_lds16(Wc + slot * 4, &Wl[0][slot * 4]);
    }

    // --- build Pt: Pt[d*32 + rr*16 + c] = s_i[d]*s_j[d] (32 pairs) ---
    for (int e = t; e < 1024; e += 256) {
        int rr = e >> 9, c = e & 15, dq = (e >> 4) & 31;
        int j = cand[rr][c];
        float4 sj = *(const float4*)(s + ((size_t)(b * N_ + j)) * D_ + dq * 4);
        float4 si = *(const float4*)(s + ((size_t)(bi0 + rr)) * D_ + dq * 4);
        int base = (dq * 4) * 32 + rr * 16 + c;
        Pt[base + 0 * 32] = si.x * sj.x;
        Pt[base + 1 * 32] = si.y * sj.y;
        Pt[base + 2 * 32] = si.z * sj.z;
        Pt[base + 3 * 32] = si.w * sj.w;
    }

    // --- acc init: exact fp32 a_i[h] + b_j[h] for 4 cands x 8 h ---
    int cg = t & 3, rr = (t >> 2) & 1;
    int hg = t >> 3;                    // 0..31, 8 h each
    int h0 = hg * 8;
    float acc[4][8];
    {
        const float* av = avec + (size_t)(bi0 + rr) * H_ + h0;
        float4 av40 = *(const float4*)(av);
        float4 av41 = *(const float4*)(av + 4);
        #pragma unroll
        for (int cc = 0; cc < 4; ++cc) {
            int j = cand[rr][cg * 4 + cc];
            const float* bv = bvec + ((size_t)(b * N_ + j)) * H_ + h0;
            float4 b40 = *(const float4*)(bv);
            float4 b41 = *(const float4*)(bv + 4);
            acc[cc][0] = av40.x + b40.x;
            acc[cc][1] = av40.y + b40.y;
            acc[cc][2] = av40.z + b40.z;
            acc[cc][3] = av40.w + b40.w;
            acc[cc][4] = av41.x + b41.x;
            acc[cc][5] = av41.y + b41.y;
            acc[cc][6] = av41.z + b41.z;
            acc[cc][7] = av41.w + b41.w;
        }
    }
    __syncthreads();   // drains chunk-0 DMA + Pt writes

    // --- K-chunked GEMM (16 chunks of 8 d), async double-buffered W ---
    int pvoff = rr * 16 + cg * 4;
    #pragma unroll 1
    for (int ch = 0; ch < 16; ++ch) {
        int cur = ch & 1;
        if (ch < 15) {
            const float* src = Wc + (size_t)(ch + 1) * DC8 * H_;
            #pragma unroll
            for (int k = 0; k < 2; ++k) {
                int slot = t + 256 * k;
                gld_lds16(src + slot * 4, &Wl[cur ^ 1][slot * 4]);
            }
        }
        int d0 = ch * DC8;
        #pragma unroll
        for (int d = 0; d < DC8; ++d) {
            float4 pv = *(const float4*)&Pt[(d0 + d) * 32 + pvoff];
            float wv[8];
            *(float4*)&wv[0] = *(const float4*)&Wl[cur][d * H_ + h0];
            *(float4*)&wv[4] = *(const float4*)&Wl[cur][d * H_ + h0 + 4];
            #pragma unroll
            for (int m = 0; m < 8; ++m) {
                acc[0][m] = fmaf(pv.x, wv[m], acc[0][m]);
                acc[1][m] = fmaf(pv.y, wv[m], acc[1][m]);
                acc[2][m] = fmaf(pv.z, wv[m], acc[2][m]);
                acc[3][m] = fmaf(pv.w, wv[m], acc[3][m]);
            }
        }
        __syncthreads();
    }

    // --- epilogue: relu * W2 partial per (r, cand), reduce over 32 hg ---
    {
        float w2v[8];
        *(float4*)&w2v[0] = *(const float4*)(W2 + h0);
        *(float4*)&w2v[4] = *(const float4*)(W2 + h0 + 4);
        #pragma unroll
        for (int cc = 0; cc < 4; ++cc) {
            float sc = 0.f;
            #pragma unroll
            for (int m = 0; m < 8; ++m)
                sc = fmaf(fmaxf(acc[cc][m], 0.f), w2v[m], sc);
            part[rr][cg * 4 + cc][hg] = sc;
        }
    }
    __syncthreads();
    if (t < 32) {
        int r2 = t >> 4, c2 = t & 15;
        float sum = b2[0];
        #pragma unroll
        for (int m = 0; m < 32; ++m) sum += part[r2][c2][m];
        rsc[r2][c2] = sum;
    }
    __syncthreads();

    // top-8 among 16 exact scores, tiebreak smaller original index
    if (t < 32) {
        int r2 = t >> 4, c2 = t & 15;
        float my = rsc[r2][c2]; int myj = cand[r2][c2];
        int rank = 0;
        #pragma unroll
        for (int c3 = 0; c3 < 16; ++c3) {
            float o = rsc[r2][c3]; int oj = cand[r2][c3];
            rank += (o > my) || (o == my && oj < myj);
        }
        if (rank < 8) sel8[r2][rank] = myj;
    }
    __syncthreads();

    // gate / w: 2 rows x 256 j, 2 per thread
    for (int e = t; e < 512; e += 256) {
        int r2 = e >> 8, jj = e & 255;
        float gv = 0.f;
        #pragma unroll
        for (int m = 0; m < 8; ++m)
            gv = (jj == sel8[r2][m]) ? 1.f : gv;
        gate[(size_t)(bi0 + r2) * N_ + jj] = gv;
        w[(size_t)(bi0 + r2) * N_ + jj]    = gv * 0.125f;
    }
    // ctx: 2 rows x 128 d, 1 per thread
    {
        int r2 = t >> 7, d = t & 127;
        float a = 0.f;
        #pragma unroll
        for (int m = 0; m < 8; ++m)
            a += s[((size_t)(b * N_ + sel8[r2][m])) * D_ + d];
        ctx[(size_t)(bi0 + r2) * D_ + d] = a * 0.125f;
    }
}

extern "C" void kernel_launch(void* const* d_in, const int* in_sizes, int n_in,
                              void* d_out, int out_size, void* d_ws, size_t ws_size,
                              hipStream_t stream)
{
    const float* s  = (const float*)d_in[0];
    const float* W1 = (const float*)d_in[1];
    const float* b1 = (const float*)d_in[2];
    const float* W2 = (const float*)d_in[3];
    const float* b2 = (const float*)d_in[4];

    float* avec = (float*)d_ws;                                           // 262144 f
    float* bvec = avec + (size_t)B_ * N_ * H_;                            // 262144 f
    unsigned short* ascu = (unsigned short*)(bvec + (size_t)B_ * N_ * H_);// 262144 us
    unsigned short* Wtu  = ascu + (size_t)B_ * N_ * N_;                   // 32768 us

    float* ctx  = (float*)d_out;
    float* gate = ctx + (size_t)B_ * N_ * D_;
    float* wout = gate + (size_t)B_ * N_ * N_;

    pre_kernel<<<640, 256, 0, stream>>>(s, W1, b1, avec, bvec, Wtu);
    approx_scores<<<512, 512, 0, stream>>>(s, Wtu, W2, b2, avec, bvec, ascu);
    finalize_kernel<<<B_ * N_ / 2, 256, 0, stream>>>(s, W1, W2, b2, avec, bvec, ascu,
                                                     ctx, gate, wout);
}